// Round 7
// baseline (555.900 us; speedup 1.0000x reference)
//
#include <hip/hip_runtime.h>
#include <cmath>

// Problem constants
#define NVOC 100
#define DIMN 200
#define LDA  256      // swizzled LDS stride for av/hv rows
#define DPD  204      // DIM + NADD
#define LDM  36       // stride for 32x32 LDS matrices
#define NTOT 8192
#define PROW 20             // k-rows per panel per k-half
#define PFLT (PROW*DIMN)    // 4000 floats per panel-half
// grid = 256 molecules (1 block/CU), block = 896 = 14 waves.
// K-split: kg = w>=7 (k 0..99 | 100..199), wc = col block. Thread tile 4r x 4c.
// W is staged HBM/L2 -> LDS in double-buffered 20-row panels (coalesced, 160
// instr/layer) instead of 1400 latency-exposed per-thread vector loads.

#define FMA4(acc, s, wv) do { \
    (acc).x = fmaf((s),(wv).x,(acc).x); \
    (acc).y = fmaf((s),(wv).y,(acc).y); \
    (acc).z = fmaf((s),(wv).z,(acc).z); \
    (acc).w = fmaf((s),(wv).w,(acc).w); } while(0)

// XOR swizzle: dword col c of row r lives at r*LDA + (c ^ 4*(r>>2)).
__device__ __forceinline__ int swz(int r, int c) {
    return (r << 8) + (c ^ (((r >> 2) & 7) << 2));
}

// Panel-staged GEMM. acc[j] = row r0+j, cols n0..n0+3 of src @ W (no bias/scale:
// deferred to combine). Stages panel p+1 (or next layer's panel 0 via Wnext)
// while computing panel p from LDS.
__device__ __forceinline__ void gemm_panels(
    const float* __restrict__ src, float* __restrict__ Wlds,
    const float* __restrict__ Wg, const float* __restrict__ Wnext,
    int parity, int kbase, int kgofs,
    int goff0, int goff1, int goff2, int loff0, int loff1, int loff2, bool h3,
    int r0, int n0, int sw, bool act, float4 acc[4])
{
    acc[0].x = acc[0].y = acc[0].z = acc[0].w = 0.f;
    acc[1] = acc[0]; acc[2] = acc[0]; acc[3] = acc[0];
    #pragma unroll 1
    for (int p = 0; p < 5; ++p) {
        const int buf = (parity + p) & 1;
        const float* Wsrc = (p < 4) ? (Wg + (p + 1) * PFLT) : Wnext;
        float4 s0, s1, s2;
        if (Wsrc) {   // issue staging loads early (latency hidden by compute)
            s0 = *(const float4*)(Wsrc + goff0);
            s1 = *(const float4*)(Wsrc + goff1);
            if (h3) s2 = *(const float4*)(Wsrc + goff2);
        }
        if (act) {
            const float* WB = Wlds + buf * (2 * PFLT) + kgofs + n0;
            #pragma unroll
            for (int kq = 0; kq < 5; ++kq) {
                const int kl = kq * 4;
                const int ks = (kbase + p * PROW + kl) ^ sw;
                const float4 a0 = *(const float4*)&src[(r0+0)*LDA + ks];
                const float4 a1 = *(const float4*)&src[(r0+1)*LDA + ks];
                const float4 a2 = *(const float4*)&src[(r0+2)*LDA + ks];
                const float4 a3 = *(const float4*)&src[(r0+3)*LDA + ks];
                const float* Wk = WB + kl * DIMN;
                const float4 w0 = *(const float4*)(Wk);
                const float4 w1 = *(const float4*)(Wk + DIMN);
                const float4 w2 = *(const float4*)(Wk + 2*DIMN);
                const float4 w3 = *(const float4*)(Wk + 3*DIMN);
                FMA4(acc[0],a0.x,w0); FMA4(acc[1],a1.x,w0); FMA4(acc[2],a2.x,w0); FMA4(acc[3],a3.x,w0);
                FMA4(acc[0],a0.y,w1); FMA4(acc[1],a1.y,w1); FMA4(acc[2],a2.y,w1); FMA4(acc[3],a3.y,w1);
                FMA4(acc[0],a0.z,w2); FMA4(acc[1],a1.z,w2); FMA4(acc[2],a2.z,w2); FMA4(acc[3],a3.z,w2);
                FMA4(acc[0],a0.w,w3); FMA4(acc[1],a1.w,w3); FMA4(acc[2],a2.w,w3); FMA4(acc[3],a3.w,w3);
            }
        }
        if (Wsrc) {   // commit staged panel to the other buffer
            float* D = Wlds + (buf ^ 1) * (2 * PFLT);
            *(float4*)(D + loff0) = s0;
            *(float4*)(D + loff1) = s1;
            if (h3) *(float4*)(D + loff2) = s2;
        }
        __syncthreads();
    }
}

__global__ __launch_bounds__(896)
void mgnn_kernel(const int*   __restrict__ atoms,
                 const float* __restrict__ dist,
                 const float* __restrict__ adducts,
                 const float* __restrict__ embed,
                 const float* __restrict__ gamma_tab,
                 const float* __restrict__ Waw,
                 const float* __restrict__ Wab,
                 const float* __restrict__ Wow,
                 const float* __restrict__ Wob,
                 const float* __restrict__ Wpw,
                 const float* __restrict__ Wpb,
                 const float* __restrict__ Wprw,
                 const float* __restrict__ Wprb,
                 float* __restrict__ out)
{
    __shared__ float  bufA[32*LDA];    // x / hv, swizzled (32 KB)
    __shared__ float  bufP[32*LDA];    // k-half-1 partials (32 KB)
    __shared__ float  Wlds[4*PFLT];    // [dbuf][khalf][20x200] W panels (64 KB)
    __shared__ float  d2s [32*LDM];
    __shared__ float  Mts [32*LDM];
    __shared__ float4 part4[64];
    __shared__ float  scale_s[32];
    __shared__ float  red16[16];
    __shared__ int    atom_s[32];
    // total ~140 KB < 160 KB

    const int mol  = blockIdx.x;
    const int t    = threadIdx.x;
    const int base = mol * 32;
    const int w    = t >> 6;
    const int lane = t & 63;
    const int kg   = (w >= 7);
    const int wc   = kg ? (w - 7) : w;
    const int c8   = lane & 7;
    const int rq   = lane >> 3;
    const int r0   = rq * 4;
    const int n0   = wc * 32 + c8 * 4;
    const bool act = (n0 < DIMN);
    const int sw   = (rq & 7) << 2;
    const int kbase = kg ? 100 : 0;
    const int kgofs = kg ? PFLT : 0;

    // staging map: 2000 float4 per panel-pair over 896 threads (linear->coalesced)
    int goff0, goff1, goff2, loff0, loff1, loff2;
    {
        int idx = t;
        int half = idx >= 1000; int rem = idx - half*1000;
        int rr = rem / 50;      int cc = (rem % 50) * 4;
        goff0 = half*20000 + rr*200 + cc; loff0 = half*PFLT + rr*200 + cc;
        idx = t + 896;
        half = idx >= 1000; rem = idx - half*1000; rr = rem / 50; cc = (rem % 50) * 4;
        goff1 = half*20000 + rr*200 + cc; loff1 = half*PFLT + rr*200 + cc;
        idx = t + 1792;
        half = idx >= 1000; rem = idx - half*1000; rr = rem / 50; cc = (rem % 50) * 4;
        goff2 = half*20000 + rr*200 + cc; loff2 = half*PFLT + rr*200 + cc;
    }
    const bool h3 = (t < 208);

    // ---- init ----
    if (t < 32) atom_s[t] = atoms[base + t];
    if (t < 512) {
        const int j  = t >> 4;
        const int c2 = (t & 15) * 2;
        const float2 dd = *(const float2*)&dist[(size_t)(base + j) * NTOT + base + c2];
        float2 q; q.x = dd.x*dd.x; q.y = dd.y*dd.y;
        *(float2*)&d2s[j*LDM + c2] = q;
    }
    for (int idx = t; idx < 32*50; idx += 896) {
        const int r  = idx / 50;
        const int c4 = (idx % 50) * 4;
        const int a  = atoms[base + r];
        *(float4*)&bufA[swz(r, c4)] = *(const float4*)&embed[a*DIMN + c4];
    }
    {   // stage layer-0 panel-0 into buf 0
        *(float4*)&Wlds[loff0] = *(const float4*)(Waw + goff0);
        *(float4*)&Wlds[loff1] = *(const float4*)(Waw + goff1);
        if (h3) *(float4*)&Wlds[loff2] = *(const float4*)(Waw + goff2);
    }
    __syncthreads();

    // ---- 6 hidden layers (norm deferred: bufA holds unnormalized x) ----
    for (int l = 0; l < 6; ++l) {
        const float* Wg = Waw + l * 40000;
        const float* Wn = (l < 5) ? (Waw + (l+1) * 40000) : Wow;
        float4 acc[4];
        gemm_panels(bufA, Wlds, Wg, Wn, l & 1, kbase, kgofs,
                    goff0, goff1, goff2, loff0, loff1, loff2, h3,
                    r0, n0, sw, act, acc);
        if (act && kg) {
            #pragma unroll
            for (int i = 0; i < 4; ++i)
                *(float4*)&bufP[swz(r0+i, n0)] = acc[i];
        }
        __syncthreads();   // B0: partials visible; GEMM reads of bufA done
        if (act && !kg) {
            const float4 b4 = *(const float4*)&Wab[l*DIMN + n0];
            #pragma unroll
            for (int i = 0; i < 4; ++i) {
                const float4 pp = *(const float4*)&bufP[swz(r0+i, n0)];
                const float sr = (l == 0) ? 1.f : scale_s[r0+i];
                acc[i].x = fmaxf(fmaf(acc[i].x + pp.x, sr, b4.x), 0.f);
                acc[i].y = fmaxf(fmaf(acc[i].y + pp.y, sr, b4.y), 0.f);
                acc[i].z = fmaxf(fmaf(acc[i].z + pp.z, sr, b4.z), 0.f);
                acc[i].w = fmaxf(fmaf(acc[i].w + pp.w, sr, b4.w), 0.f);
                *(float4*)&bufA[swz(r0+i, n0)] = acc[i];   // hv
            }
        }
        if (t < 512) {   // Mts[j][r] = exp(-g[j]*d2[r][j])
            const int j  = t >> 4;
            const int rr = (t & 15) * 2;
            const float g = gamma_tab[l*NVOC + atom_s[j]];
            const float2 d = *(const float2*)&d2s[j*LDM + rr];
            Mts[j*LDM + rr]     = expf(-g*d.x);
            Mts[j*LDM + rr + 1] = expf(-g*d.y);
        }
        __syncthreads();   // B2: hv + Mts visible

        float4 p4; p4.x = p4.y = p4.z = p4.w = 0.f;
        if (act && !kg) {
            // x_next = hv + M@hv (acc holds this thread's hv tile)
            #pragma unroll 4
            for (int jj = 0; jj < 32; ++jj) {
                const float4 m4 = *(const float4*)&Mts[jj*LDM + r0];
                const float4 h4 = *(const float4*)&bufA[swz(jj, n0)];
                FMA4(acc[0], m4.x, h4);
                FMA4(acc[1], m4.y, h4);
                FMA4(acc[2], m4.z, h4);
                FMA4(acc[3], m4.w, h4);
            }
            p4.x = acc[0].x*acc[0].x; p4.x = fmaf(acc[0].y,acc[0].y,p4.x);
            p4.x = fmaf(acc[0].z,acc[0].z,p4.x); p4.x = fmaf(acc[0].w,acc[0].w,p4.x);
            p4.y = acc[1].x*acc[1].x; p4.y = fmaf(acc[1].y,acc[1].y,p4.y);
            p4.y = fmaf(acc[1].z,acc[1].z,p4.y); p4.y = fmaf(acc[1].w,acc[1].w,p4.y);
            p4.z = acc[2].x*acc[2].x; p4.z = fmaf(acc[2].y,acc[2].y,p4.z);
            p4.z = fmaf(acc[2].z,acc[2].z,p4.z); p4.z = fmaf(acc[2].w,acc[2].w,p4.z);
            p4.w = acc[3].x*acc[3].x; p4.w = fmaf(acc[3].y,acc[3].y,p4.w);
            p4.w = fmaf(acc[3].z,acc[3].z,p4.w); p4.w = fmaf(acc[3].w,acc[3].w,p4.w);
        }
        #pragma unroll
        for (int m = 1; m < 8; m <<= 1) {
            p4.x += __shfl_xor(p4.x, m);
            p4.y += __shfl_xor(p4.y, m);
            p4.z += __shfl_xor(p4.z, m);
            p4.w += __shfl_xor(p4.w, m);
        }
        if (act && !kg && c8 == 0) part4[wc*8 + rq] = p4;
        __syncthreads();   // B3: M@hv reads done + part4 visible
        if (act && !kg) {
            #pragma unroll
            for (int i = 0; i < 4; ++i)
                *(float4*)&bufA[swz(r0+i, n0)] = acc[i];   // UNNORMALIZED x
        }
        if (t < 32) {
            const float* pf = (const float*)part4;
            const int rqq = t >> 2, cm = t & 3;
            float s = 0.f;
            #pragma unroll
            for (int ww = 0; ww < 7; ++ww) s += pf[((ww*8 + rqq) << 2) + cm];
            scale_s[t] = 1.0f / fmaxf(sqrtf(s), 1e-12f);
        }
        __syncthreads();   // B4: x + scale visible (next layer's panel0 staged)
    }

    // ---- 3 out layers (deferred scale applied only in the first) ----
    for (int ol = 0; ol < 3; ++ol) {
        const float* Wg = Wow + ol * 40000;
        const float* Wn = (ol < 2) ? (Wow + (ol+1) * 40000) : nullptr;
        float4 acc[4];
        gemm_panels(bufA, Wlds, Wg, Wn, (6 + ol) & 1, kbase, kgofs,
                    goff0, goff1, goff2, loff0, loff1, loff2, h3,
                    r0, n0, sw, act, acc);
        if (act && kg) {
            #pragma unroll
            for (int i = 0; i < 4; ++i)
                *(float4*)&bufP[swz(r0+i, n0)] = acc[i];
        }
        __syncthreads();
        if (act && !kg) {
            const float4 b4 = *(const float4*)&Wob[ol*DIMN + n0];
            #pragma unroll
            for (int i = 0; i < 4; ++i) {
                const float4 pp = *(const float4*)&bufP[swz(r0+i, n0)];
                const float sr = (ol == 0) ? scale_s[r0+i] : 1.f;
                acc[i].x = fmaxf(fmaf(acc[i].x + pp.x, sr, b4.x), 0.f);
                acc[i].y = fmaxf(fmaf(acc[i].y + pp.y, sr, b4.y), 0.f);
                acc[i].z = fmaxf(fmaf(acc[i].z + pp.z, sr, b4.z), 0.f);
                acc[i].w = fmaxf(fmaf(acc[i].w + pp.w, sr, b4.w), 0.f);
                *(float4*)&bufA[swz(r0+i, n0)] = acc[i];
            }
        }
        __syncthreads();
    }

    // ---- molecule sum + adduct concat (d2s reused for mv buffers) ----
    float* mv0 = d2s;
    float* mv1 = d2s + 256;
    if (t < DIMN) {
        float s = 0.f;
        #pragma unroll 4
        for (int r = 0; r < 32; ++r)
            s += bufA[(r << 8) + (t ^ (((r >> 2) & 7) << 2))];
        mv0[t] = s;
    } else if (t < DPD) {
        mv0[t] = adducts[mol*4 + (t - 200)];
    }
    __syncthreads();

    // ---- 3 pred layers on [204] vector ----
    float* pc = mv0;
    float* pn = mv1;
    for (int l = 0; l < 3; ++l) {
        if (t < DPD) {
            float acc = Wpb[l*DPD + t];
            const float* Wl = Wpw + l*DPD*DPD;
            #pragma unroll 4
            for (int k = 0; k < DPD; ++k)
                acc = fmaf(pc[k], Wl[k*DPD + t], acc);
            pn[t] = fmaxf(acc, 0.f);
        }
        __syncthreads();
        float* tp = pc; pc = pn; pn = tp;
    }

    // ---- final property head ----
    float v = (t < DPD) ? pc[t] * Wprw[t] : 0.f;
    #pragma unroll
    for (int m = 1; m < 64; m <<= 1) v += __shfl_xor(v, m);
    if (lane == 0) red16[w] = v;
    __syncthreads();
    if (t == 0) {
        float s = Wprb[0];
        #pragma unroll
        for (int ww = 0; ww < 14; ++ww) s += red16[ww];
        out[mol] = s;
    }
}

extern "C" void kernel_launch(void* const* d_in, const int* in_sizes, int n_in,
                              void* d_out, int out_size, void* d_ws, size_t ws_size,
                              hipStream_t stream) {
    const int*   atoms   = (const int*)  d_in[0];
    const float* dist    = (const float*)d_in[1];
    const float* adducts = (const float*)d_in[2];
    const float* embed   = (const float*)d_in[3];
    const float* gamma_t = (const float*)d_in[4];
    const float* Waw     = (const float*)d_in[5];
    const float* Wab     = (const float*)d_in[6];
    const float* Wow     = (const float*)d_in[7];
    const float* Wob     = (const float*)d_in[8];
    const float* Wpw     = (const float*)d_in[9];
    const float* Wpb     = (const float*)d_in[10];
    const float* Wprw    = (const float*)d_in[11];
    const float* Wprb    = (const float*)d_in[12];
    (void)in_sizes; (void)n_in; (void)d_ws; (void)ws_size; (void)out_size;

    mgnn_kernel<<<dim3(256), dim3(896), 0, stream>>>(
        atoms, dist, adducts, embed, gamma_t,
        Waw, Wab, Wow, Wob, Wpw, Wpb, Wprw, Wprb,
        (float*)d_out);
}

// Round 8
// 524.210 us; speedup vs baseline: 1.0605x; 1.0605x over previous
//
#include <hip/hip_runtime.h>
#include <cmath>

// Problem constants
#define NVOC 100
#define DIMN 200
#define LDA  256      // swizzled LDS stride for x/hv rows
#define DPD  204      // DIM + NADD
#define LDM  36       // stride for 32x32 LDS matrices
#define NTOT 8192
// grid = 256 molecules (1 block/CU), block = 896 = 14 waves.
// K-split: kg = w>=7 (k 0..99 | 100..199), wc = col block. Thread tile 4r x 4c.
// R6 structure (best: direct W loads from L2) + deferred row-norm (barriers
// 5->3/layer), Mts/exp on waves 6..13 (overlaps combine on waves 0..6), and an
// 8-row W register prefetch issued at B2 to cover the K-loop's cold start.

#define FMA4(acc, s, wv) do { \
    (acc).x = fmaf((s),(wv).x,(acc).x); \
    (acc).y = fmaf((s),(wv).y,(acc).y); \
    (acc).z = fmaf((s),(wv).z,(acc).z); \
    (acc).w = fmaf((s),(wv).w,(acc).w); } while(0)

// XOR swizzle: dword col c of row r lives at r*LDA + (c ^ 4*(r>>2)).
__device__ __forceinline__ int swz(int r, int c) {
    return (r << 8) + (c ^ (((r >> 2) & 7) << 2));
}

// Prefetch 8 W rows (k = kbase..kbase+7) for this thread's col quad.
__device__ __forceinline__ void prefW(const float* __restrict__ Wg,
                                      int kbase, int n0, float4 wpre[8]) {
    const float* p = Wg + kbase * DIMN + n0;
    #pragma unroll
    for (int i = 0; i < 8; ++i) wpre[i] = *(const float4*)(p + i * DIMN);
}

#define FMA_BLK() do { \
    FMA4(acc[0],a0.x,w0); FMA4(acc[1],a1.x,w0); FMA4(acc[2],a2.x,w0); FMA4(acc[3],a3.x,w0); \
    FMA4(acc[0],a0.y,w1); FMA4(acc[1],a1.y,w1); FMA4(acc[2],a2.y,w1); FMA4(acc[3],a3.y,w1); \
    FMA4(acc[0],a0.z,w2); FMA4(acc[1],a1.z,w2); FMA4(acc[2],a2.z,w2); FMA4(acc[3],a3.z,w2); \
    FMA4(acc[0],a0.w,w3); FMA4(acc[1],a1.w,w3); FMA4(acc[2],a2.w,w3); FMA4(acc[3],a3.w,w3); } while(0)

// Half-K GEMM, zero-init (bias/scale deferred to combine). First 2 k-iters
// consume the prefetched W rows; rest load directly (R6 scheme).
__device__ __forceinline__ void gemm_half(const float* src,
                                          const float* __restrict__ Wg,
                                          int kbase, int r0, int n0, int sw,
                                          float4 acc[4], const float4 wpre[8])
{
    acc[0].x = acc[0].y = acc[0].z = acc[0].w = 0.f;
    acc[1] = acc[0]; acc[2] = acc[0]; acc[3] = acc[0];
    #pragma unroll
    for (int kq = 0; kq < 2; ++kq) {
        const int ks = (kbase + kq * 4) ^ sw;
        const float4 a0 = *(const float4*)&src[(r0+0)*LDA + ks];
        const float4 a1 = *(const float4*)&src[(r0+1)*LDA + ks];
        const float4 a2 = *(const float4*)&src[(r0+2)*LDA + ks];
        const float4 a3 = *(const float4*)&src[(r0+3)*LDA + ks];
        const float4 w0 = wpre[kq*4+0];
        const float4 w1 = wpre[kq*4+1];
        const float4 w2 = wpre[kq*4+2];
        const float4 w3 = wpre[kq*4+3];
        FMA_BLK();
    }
    #pragma unroll 2
    for (int k0 = kbase + 8; k0 < kbase + 100; k0 += 4) {
        const int ks = k0 ^ sw;
        const float4 a0 = *(const float4*)&src[(r0+0)*LDA + ks];
        const float4 a1 = *(const float4*)&src[(r0+1)*LDA + ks];
        const float4 a2 = *(const float4*)&src[(r0+2)*LDA + ks];
        const float4 a3 = *(const float4*)&src[(r0+3)*LDA + ks];
        const float* Wk = Wg + k0*DIMN + n0;
        const float4 w0 = *(const float4*)(Wk);
        const float4 w1 = *(const float4*)(Wk + DIMN);
        const float4 w2 = *(const float4*)(Wk + 2*DIMN);
        const float4 w3 = *(const float4*)(Wk + 3*DIMN);
        FMA_BLK();
    }
}

// combine: acc[i] = relu((acc[i] + bufP[i]) * SR + b4), write to bufA
#define CMB(i, SR) do { \
    const float4 pp = *(const float4*)&bufP[swz(r0+i, n0)]; \
    acc[i].x = fmaxf(fmaf(acc[i].x + pp.x, (SR), b4.x), 0.f); \
    acc[i].y = fmaxf(fmaf(acc[i].y + pp.y, (SR), b4.y), 0.f); \
    acc[i].z = fmaxf(fmaf(acc[i].z + pp.z, (SR), b4.z), 0.f); \
    acc[i].w = fmaxf(fmaf(acc[i].w + pp.w, (SR), b4.w), 0.f); \
    *(float4*)&bufA[swz(r0+i, n0)] = acc[i]; } while(0)

__global__ __launch_bounds__(896)
void mgnn_kernel(const int*   __restrict__ atoms,
                 const float* __restrict__ dist,
                 const float* __restrict__ adducts,
                 const float* __restrict__ embed,
                 const float* __restrict__ gamma_tab,
                 const float* __restrict__ Waw,
                 const float* __restrict__ Wab,
                 const float* __restrict__ Wow,
                 const float* __restrict__ Wob,
                 const float* __restrict__ Wpw,
                 const float* __restrict__ Wpb,
                 const float* __restrict__ Wprw,
                 const float* __restrict__ Wprb,
                 float* __restrict__ out)
{
    __shared__ float  bufA[32*LDA];   // x / hv, swizzled (32 KB)
    __shared__ float  bufP[32*LDA];   // k-half-1 partials (32 KB)
    __shared__ float  d2s [32*LDM];
    __shared__ float  Mts [32*LDM];   // Mts[j][r] = M[r][j]
    __shared__ float4 part4[64];      // norm partials [wc][rq]
    __shared__ float  scale_s[32];
    __shared__ float  red16[16];
    __shared__ int    atom_s[32];

    const int mol  = blockIdx.x;
    const int t    = threadIdx.x;
    const int base = mol * 32;
    const int w    = t >> 6;          // wave 0..13
    const int lane = t & 63;
    const int kg   = (w >= 7);
    const int wc   = kg ? (w - 7) : w;
    const int c8   = lane & 7;
    const int rq   = lane >> 3;
    const int r0   = rq * 4;
    const int n0   = wc * 32 + c8 * 4;
    const bool act = (n0 < DIMN);
    const int sw   = (rq & 7) << 2;
    const int kbase = kg ? 100 : 0;

    float4 wpre[8];

    // ---- init ----
    if (t < 32) atom_s[t] = atoms[base + t];
    if (t < 512) {
        const int j  = t >> 4;
        const int c2 = (t & 15) * 2;
        const float2 dd = *(const float2*)&dist[(size_t)(base + j) * NTOT + base + c2];
        float2 q; q.x = dd.x*dd.x; q.y = dd.y*dd.y;
        *(float2*)&d2s[j*LDM + c2] = q;
    }
    for (int idx = t; idx < 32*50; idx += 896) {
        const int r  = idx / 50;
        const int c4 = (idx % 50) * 4;
        const int a  = atoms[base + r];
        *(float4*)&bufA[swz(r, c4)] = *(const float4*)&embed[a*DIMN + c4];
    }
    if (act) prefW(Waw, kbase, n0, wpre);   // layer-0 W head
    __syncthreads();

    // ---- 6 hidden layers (bufA holds UNNORMALIZED x; scale folded forward) ----
    for (int l = 0; l < 6; ++l) {
        float4 acc[4];
        if (act)
            gemm_half(bufA, Waw + l*40000, kbase, r0, n0, sw, acc, wpre);
        if (act && kg) {
            #pragma unroll
            for (int i = 0; i < 4; ++i)
                *(float4*)&bufP[swz(r0+i, n0)] = acc[i];
        }
        __syncthreads();   // B0: partials visible; GEMM reads of bufA done

        if (act && !kg) {  // combine on waves 0..6: hv = relu((g0+g1)*s_prev + b)
            const float4 b4 = *(const float4*)&Wab[l*DIMN + n0];
            float4 sc4;
            if (l == 0) { sc4.x = sc4.y = sc4.z = sc4.w = 1.f; }
            else        { sc4 = *(const float4*)&scale_s[r0]; }
            CMB(0, sc4.x); CMB(1, sc4.y); CMB(2, sc4.z); CMB(3, sc4.w);
        }
        if (t >= 384) {    // Mts on waves 6..13 (overlaps combine)
            const int tm = t - 384;
            const int j  = tm >> 4;
            const int rr = (tm & 15) * 2;
            const float g = gamma_tab[l*NVOC + atom_s[j]];
            const float2 d = *(const float2*)&d2s[j*LDM + rr];
            Mts[j*LDM + rr]     = expf(-g*d.x);
            Mts[j*LDM + rr + 1] = expf(-g*d.y);
        }
        __syncthreads();   // B2: hv + Mts visible

        // prefetch next layer's W head (in flight across M@hv + B3)
        if (act) prefW((l < 5) ? (Waw + (l+1)*40000) : Wow, kbase, n0, wpre);

        float4 p4; p4.x = p4.y = p4.z = p4.w = 0.f;
        if (act && !kg) {
            // x_next = hv + M@hv (acc holds this thread's hv tile)
            #pragma unroll 4
            for (int jj = 0; jj < 32; ++jj) {
                const float4 m4 = *(const float4*)&Mts[jj*LDM + r0];
                const float4 h4 = *(const float4*)&bufA[swz(jj, n0)];
                FMA4(acc[0], m4.x, h4);
                FMA4(acc[1], m4.y, h4);
                FMA4(acc[2], m4.z, h4);
                FMA4(acc[3], m4.w, h4);
            }
            p4.x = acc[0].x*acc[0].x; p4.x = fmaf(acc[0].y,acc[0].y,p4.x);
            p4.x = fmaf(acc[0].z,acc[0].z,p4.x); p4.x = fmaf(acc[0].w,acc[0].w,p4.x);
            p4.y = acc[1].x*acc[1].x; p4.y = fmaf(acc[1].y,acc[1].y,p4.y);
            p4.y = fmaf(acc[1].z,acc[1].z,p4.y); p4.y = fmaf(acc[1].w,acc[1].w,p4.y);
            p4.z = acc[2].x*acc[2].x; p4.z = fmaf(acc[2].y,acc[2].y,p4.z);
            p4.z = fmaf(acc[2].z,acc[2].z,p4.z); p4.z = fmaf(acc[2].w,acc[2].w,p4.z);
            p4.w = acc[3].x*acc[3].x; p4.w = fmaf(acc[3].y,acc[3].y,p4.w);
            p4.w = fmaf(acc[3].z,acc[3].z,p4.w); p4.w = fmaf(acc[3].w,acc[3].w,p4.w);
        }
        #pragma unroll
        for (int m = 1; m < 8; m <<= 1) {
            p4.x += __shfl_xor(p4.x, m);
            p4.y += __shfl_xor(p4.y, m);
            p4.z += __shfl_xor(p4.z, m);
            p4.w += __shfl_xor(p4.w, m);
        }
        if (act && !kg && c8 == 0) part4[wc*8 + rq] = p4;
        if (act && !kg) {
            #pragma unroll
            for (int i = 0; i < 4; ++i)
                *(float4*)&bufA[swz(r0+i, n0)] = acc[i];   // UNNORMALIZED x
        }
        __syncthreads();   // B3: x + part4 visible
        if (t < 32) {      // scale consumed after next layer's B0
            const float* pf = (const float*)part4;
            const int rqq = t >> 2, cm = t & 3;
            float s = 0.f;
            #pragma unroll
            for (int ww = 0; ww < 7; ++ww) s += pf[((ww*8 + rqq) << 2) + cm];
            scale_s[t] = 1.0f / fmaxf(sqrtf(s), 1e-12f);
        }
    }

    // ---- 3 out layers (deferred scale applied only in the first) ----
    for (int ol = 0; ol < 3; ++ol) {
        float4 acc[4];
        if (act)
            gemm_half(bufA, Wow + ol*40000, kbase, r0, n0, sw, acc, wpre);
        if (act && ol < 2) prefW(Wow + (ol+1)*40000, kbase, n0, wpre);
        if (act && kg) {
            #pragma unroll
            for (int i = 0; i < 4; ++i)
                *(float4*)&bufP[swz(r0+i, n0)] = acc[i];
        }
        __syncthreads();
        if (act && !kg) {
            const float4 b4 = *(const float4*)&Wob[ol*DIMN + n0];
            float4 sc4;
            if (ol == 0) { sc4 = *(const float4*)&scale_s[r0]; }
            else         { sc4.x = sc4.y = sc4.z = sc4.w = 1.f; }
            CMB(0, sc4.x); CMB(1, sc4.y); CMB(2, sc4.z); CMB(3, sc4.w);
        }
        __syncthreads();
    }

    // ---- molecule sum + adduct concat (d2s reused for mv buffers) ----
    float* mv0 = d2s;
    float* mv1 = d2s + 256;
    if (t < DIMN) {
        float s = 0.f;
        #pragma unroll 4
        for (int r = 0; r < 32; ++r)
            s += bufA[(r << 8) + (t ^ (((r >> 2) & 7) << 2))];
        mv0[t] = s;
    } else if (t < DPD) {
        mv0[t] = adducts[mol*4 + (t - 200)];
    }
    __syncthreads();

    // ---- 3 pred layers on [204] vector ----
    float* pc = mv0;
    float* pn = mv1;
    for (int l = 0; l < 3; ++l) {
        if (t < DPD) {
            float acc = Wpb[l*DPD + t];
            const float* Wl = Wpw + l*DPD*DPD;
            #pragma unroll 4
            for (int k = 0; k < DPD; ++k)
                acc = fmaf(pc[k], Wl[k*DPD + t], acc);
            pn[t] = fmaxf(acc, 0.f);
        }
        __syncthreads();
        float* tp = pc; pc = pn; pn = tp;
    }

    // ---- final property head ----
    float v = (t < DPD) ? pc[t] * Wprw[t] : 0.f;
    #pragma unroll
    for (int m = 1; m < 64; m <<= 1) v += __shfl_xor(v, m);
    if (lane == 0) red16[w] = v;
    __syncthreads();
    if (t == 0) {
        float s = Wprb[0];
        #pragma unroll
        for (int ww = 0; ww < 14; ++ww) s += red16[ww];
        out[mol] = s;
    }
}

extern "C" void kernel_launch(void* const* d_in, const int* in_sizes, int n_in,
                              void* d_out, int out_size, void* d_ws, size_t ws_size,
                              hipStream_t stream) {
    const int*   atoms   = (const int*)  d_in[0];
    const float* dist    = (const float*)d_in[1];
    const float* adducts = (const float*)d_in[2];
    const float* embed   = (const float*)d_in[3];
    const float* gamma_t = (const float*)d_in[4];
    const float* Waw     = (const float*)d_in[5];
    const float* Wab     = (const float*)d_in[6];
    const float* Wow     = (const float*)d_in[7];
    const float* Wob     = (const float*)d_in[8];
    const float* Wpw     = (const float*)d_in[9];
    const float* Wpb     = (const float*)d_in[10];
    const float* Wprw    = (const float*)d_in[11];
    const float* Wprb    = (const float*)d_in[12];
    (void)in_sizes; (void)n_in; (void)d_ws; (void)ws_size; (void)out_size;

    mgnn_kernel<<<dim3(256), dim3(896), 0, stream>>>(
        atoms, dist, adducts, embed, gamma_t,
        Waw, Wab, Wow, Wob, Wpw, Wpb, Wprw, Wprb,
        (float*)d_out);
}

// Round 9
// 520.556 us; speedup vs baseline: 1.0679x; 1.0070x over previous
//
#include <hip/hip_runtime.h>
#include <cmath>

// Problem constants
#define NVOC 100
#define DIMN 200
#define LDA  256      // swizzled LDS stride for x/hv rows
#define DPD  204      // DIM + NADD
#define LDM  36       // stride for 32x32 LDS matrices
#define NTOT 8192
#define PFL   8000    // floats per 40-row W panel (40*200)
#define PBUFF 8192    // panel buffer slot in floats (32 KB incl. 768 B overrun pad)
// grid = 256 molecules (1 block/CU), block = 896 = 14 waves.
// W is staged HBM/L2 -> LDS via async global_load_lds (no registers, no vmcnt
// in the K-loop): double-buffered 40-row panels, 32 x 1KB issues per panel
// spread over the 14 waves, staged one panel ahead. K-split is by even/odd
// k-quads so both k-groups consume the same panel stream. Thread tile 4r x 4c.

#define FMA4(acc, s, wv) do { \
    (acc).x = fmaf((s),(wv).x,(acc).x); \
    (acc).y = fmaf((s),(wv).y,(acc).y); \
    (acc).z = fmaf((s),(wv).z,(acc).z); \
    (acc).w = fmaf((s),(wv).w,(acc).w); } while(0)

// XOR swizzle: dword col c of row r lives at r*LDA + (c ^ 4*(r>>2)).
__device__ __forceinline__ int swz(int r, int c) {
    return (r << 8) + (c ^ (((r >> 2) & 7) << 2));
}

#define FMA_BLK() do { \
    FMA4(acc[0],a0.x,w0); FMA4(acc[1],a1.x,w0); FMA4(acc[2],a2.x,w0); FMA4(acc[3],a3.x,w0); \
    FMA4(acc[0],a0.y,w1); FMA4(acc[1],a1.y,w1); FMA4(acc[2],a2.y,w1); FMA4(acc[3],a3.y,w1); \
    FMA4(acc[0],a0.z,w2); FMA4(acc[1],a1.z,w2); FMA4(acc[2],a2.z,w2); FMA4(acc[3],a3.z,w2); \
    FMA4(acc[0],a0.w,w3); FMA4(acc[1],a1.w,w3); FMA4(acc[2],a2.w,w3); FMA4(acc[3],a3.w,w3); } while(0)

typedef __attribute__((address_space(3))) unsigned int        lds_u32_t;
typedef const __attribute__((address_space(1))) unsigned int  glb_u32_t;

// Async-stage one 32000B W panel (40 rows) into LDS: 32 x 1KB issues, wave w
// takes issues j = w, w+14, w+28. LDS dest is wave-uniform base + lane*16
// (hardware-applied). gclamp = last valid 16B of the W allocation (overrun
// issues re-read the tail; the padded LDS region is never consumed).
__device__ __forceinline__ void stage_panel(const float* gp, const float* gclamp,
                                            float* lb, int w, int lane)
{
    const char* g0 = (const char*)gp;
    const char* gc = (const char*)gclamp;
    for (int j = w; j < 32; j += 14) {
        const char* ga = g0 + (j * 1024 + lane * 16);
        if (ga > gc) ga = gc;
        __builtin_amdgcn_global_load_lds((glb_u32_t*)ga,
                                         (lds_u32_t*)((char*)lb + j * 1024),
                                         16, 0, 0);
    }
}

// One panel's worth of this thread's k-quads (5 of the 10, parity = kg).
__device__ __forceinline__ void gemm_panel5(const float* __restrict__ src,
                                            const float* __restrict__ Wb,
                                            int kbase, int kg, int r0, int n0,
                                            int sw, float4 acc[4])
{
    #pragma unroll
    for (int i = 0; i < 5; ++i) {
        const int kk = (2*i + kg) * 4;          // within-panel row 0..36
        const int ks = (kbase + kk) ^ sw;       // bufA dword col (global k)
        const float4 a0 = *(const float4*)&src[(r0+0)*LDA + ks];
        const float4 a1 = *(const float4*)&src[(r0+1)*LDA + ks];
        const float4 a2 = *(const float4*)&src[(r0+2)*LDA + ks];
        const float4 a3 = *(const float4*)&src[(r0+3)*LDA + ks];
        const float* Wk = Wb + kk*DIMN + n0;
        const float4 w0 = *(const float4*)(Wk);
        const float4 w1 = *(const float4*)(Wk + DIMN);
        const float4 w2 = *(const float4*)(Wk + 2*DIMN);
        const float4 w3 = *(const float4*)(Wk + 3*DIMN);
        FMA_BLK();
    }
}

// combine: acc[i] = relu((acc[i] + bufP[i]) * SR + b4), write to bufA
#define CMB(i, SR) do { \
    const float4 pp = *(const float4*)&bufP[swz(r0+i, n0)]; \
    acc[i].x = fmaxf(fmaf(acc[i].x + pp.x, (SR), b4.x), 0.f); \
    acc[i].y = fmaxf(fmaf(acc[i].y + pp.y, (SR), b4.y), 0.f); \
    acc[i].z = fmaxf(fmaf(acc[i].z + pp.z, (SR), b4.z), 0.f); \
    acc[i].w = fmaxf(fmaf(acc[i].w + pp.w, (SR), b4.w), 0.f); \
    *(float4*)&bufA[swz(r0+i, n0)] = acc[i]; } while(0)

__global__ __launch_bounds__(896)
void mgnn_kernel(const int*   __restrict__ atoms,
                 const float* __restrict__ dist,
                 const float* __restrict__ adducts,
                 const float* __restrict__ embed,
                 const float* __restrict__ gamma_tab,
                 const float* __restrict__ Waw,
                 const float* __restrict__ Wab,
                 const float* __restrict__ Wow,
                 const float* __restrict__ Wob,
                 const float* __restrict__ Wpw,
                 const float* __restrict__ Wpb,
                 const float* __restrict__ Wprw,
                 const float* __restrict__ Wprb,
                 float* __restrict__ out)
{
    __shared__ __align__(16) float Wlds[2*PBUFF];   // W panel double buffer (64 KB)
    __shared__ float  bufA[32*LDA];   // x / hv, swizzled (32 KB)
    __shared__ float  bufP[32*LDA];   // odd-k-quad partials (32 KB)
    __shared__ float  d2s [32*LDM];
    __shared__ float  Mts [32*LDM];   // Mts[j][r] = M[r][j]
    __shared__ float4 part4[64];      // norm partials [wc][rq]
    __shared__ float  scale_s[32];
    __shared__ float  red16[16];
    __shared__ int    atom_s[32];
    // total ~141.5 KB < 160 KB

    const int mol  = blockIdx.x;
    const int t    = threadIdx.x;
    const int base = mol * 32;
    const int w    = t >> 6;          // wave 0..13
    const int lane = t & 63;
    const int kg   = (w >= 7);        // k-quad parity group
    const int wc   = kg ? (w - 7) : w;
    const int c8   = lane & 7;
    const int rq   = lane >> 3;
    const int r0   = rq * 4;
    const int n0   = wc * 32 + c8 * 4;
    const bool act = (n0 < DIMN);
    const int sw   = (rq & 7) << 2;

    const float* WawClamp = Waw + 6*40000 - 4;   // last valid 16B of Waw
    const float* WowClamp = Wow + 3*40000 - 4;   // last valid 16B of Wow

    // ---- init (layer-0 panel-0 staged async during setup) ----
    stage_panel(Waw, WawClamp, &Wlds[0], w, lane);
    if (t < 32) atom_s[t] = atoms[base + t];
    if (t < 512) {
        const int j  = t >> 4;
        const int c2 = (t & 15) * 2;
        const float2 dd = *(const float2*)&dist[(size_t)(base + j) * NTOT + base + c2];
        float2 q; q.x = dd.x*dd.x; q.y = dd.y*dd.y;
        *(float2*)&d2s[j*LDM + c2] = q;
    }
    for (int idx = t; idx < 32*50; idx += 896) {
        const int r  = idx / 50;
        const int c4 = (idx % 50) * 4;
        const int a  = atoms[base + r];
        *(float4*)&bufA[swz(r, c4)] = *(const float4*)&embed[a*DIMN + c4];
    }
    __syncthreads();   // drains staging vmcnt; panel 0 + inputs visible

    int par = 0;       // LDS buffer holding the current GEMM's panel 0

    // ---- 6 hidden layers (bufA holds UNNORMALIZED x; scale folded forward) ----
    for (int l = 0; l < 6; ++l) {
        const float* Wg = Waw + l*40000;
        float4 acc[4];
        acc[0].x=acc[0].y=acc[0].z=acc[0].w=0.f; acc[1]=acc[0]; acc[2]=acc[0]; acc[3]=acc[0];
        #pragma unroll 1
        for (int p = 0; p < 5; ++p) {
            const float* nW; const float* nC;
            if (p < 4) { nW = Wg + (p+1)*PFL; nC = WawClamp; }
            else if (l < 5) { nW = Waw + (l+1)*40000; nC = WawClamp; }
            else { nW = Wow; nC = WowClamp; }
            stage_panel(nW, nC, &Wlds[((par+p+1)&1)*PBUFF], w, lane);
            if (act)
                gemm_panel5(bufA, &Wlds[((par+p)&1)*PBUFF], p*40, kg, r0, n0, sw, acc);
            if (p == 4 && act && kg) {
                #pragma unroll
                for (int i = 0; i < 4; ++i)
                    *(float4*)&bufP[swz(r0+i, n0)] = acc[i];
            }
            __syncthreads();   // panel p+1 staged; (p==4) partials visible
        }
        par ^= 1;

        if (act && !kg) {  // combine: hv = relu((even+odd)*s_prev + b)
            const float4 b4 = *(const float4*)&Wab[l*DIMN + n0];
            float4 sc4;
            if (l == 0) { sc4.x = sc4.y = sc4.z = sc4.w = 1.f; }
            else        { sc4 = *(const float4*)&scale_s[r0]; }
            CMB(0, sc4.x); CMB(1, sc4.y); CMB(2, sc4.z); CMB(3, sc4.w);
        }
        if (t >= 384) {    // Mts on waves 6..13 (overlaps combine)
            const int tm = t - 384;
            const int j  = tm >> 4;
            const int rr = (tm & 15) * 2;
            const float g = gamma_tab[l*NVOC + atom_s[j]];
            const float2 d = *(const float2*)&d2s[j*LDM + rr];
            Mts[j*LDM + rr]     = expf(-g*d.x);
            Mts[j*LDM + rr + 1] = expf(-g*d.y);
        }
        __syncthreads();   // B2: hv + Mts visible

        float4 p4; p4.x = p4.y = p4.z = p4.w = 0.f;
        if (act && !kg) {
            // x_next = hv + M@hv (acc holds this thread's hv tile)
            #pragma unroll 4
            for (int jj = 0; jj < 32; ++jj) {
                const float4 m4 = *(const float4*)&Mts[jj*LDM + r0];
                const float4 h4 = *(const float4*)&bufA[swz(jj, n0)];
                FMA4(acc[0], m4.x, h4);
                FMA4(acc[1], m4.y, h4);
                FMA4(acc[2], m4.z, h4);
                FMA4(acc[3], m4.w, h4);
            }
            p4.x = acc[0].x*acc[0].x; p4.x = fmaf(acc[0].y,acc[0].y,p4.x);
            p4.x = fmaf(acc[0].z,acc[0].z,p4.x); p4.x = fmaf(acc[0].w,acc[0].w,p4.x);
            p4.y = acc[1].x*acc[1].x; p4.y = fmaf(acc[1].y,acc[1].y,p4.y);
            p4.y = fmaf(acc[1].z,acc[1].z,p4.y); p4.y = fmaf(acc[1].w,acc[1].w,p4.y);
            p4.z = acc[2].x*acc[2].x; p4.z = fmaf(acc[2].y,acc[2].y,p4.z);
            p4.z = fmaf(acc[2].z,acc[2].z,p4.z); p4.z = fmaf(acc[2].w,acc[2].w,p4.z);
            p4.w = acc[3].x*acc[3].x; p4.w = fmaf(acc[3].y,acc[3].y,p4.w);
            p4.w = fmaf(acc[3].z,acc[3].z,p4.w); p4.w = fmaf(acc[3].w,acc[3].w,p4.w);
        }
        #pragma unroll
        for (int m = 1; m < 8; m <<= 1) {
            p4.x += __shfl_xor(p4.x, m);
            p4.y += __shfl_xor(p4.y, m);
            p4.z += __shfl_xor(p4.z, m);
            p4.w += __shfl_xor(p4.w, m);
        }
        if (act && !kg && c8 == 0) part4[wc*8 + rq] = p4;
        if (act && !kg) {
            #pragma unroll
            for (int i = 0; i < 4; ++i)
                *(float4*)&bufA[swz(r0+i, n0)] = acc[i];   // UNNORMALIZED x
        }
        __syncthreads();   // B3: x + part4 visible
        if (t < 32) {      // scale consumed in next layer's combine
            const float* pf = (const float*)part4;
            const int rqq = t >> 2, cm = t & 3;
            float s = 0.f;
            #pragma unroll
            for (int ww = 0; ww < 7; ++ww) s += pf[((ww*8 + rqq) << 2) + cm];
            scale_s[t] = 1.0f / fmaxf(sqrtf(s), 1e-12f);
        }
    }

    // ---- 3 out layers (deferred scale applied only in the first) ----
    for (int ol = 0; ol < 3; ++ol) {
        const float* Wg = Wow + ol*40000;
        float4 acc[4];
        acc[0].x=acc[0].y=acc[0].z=acc[0].w=0.f; acc[1]=acc[0]; acc[2]=acc[0]; acc[3]=acc[0];
        #pragma unroll 1
        for (int p = 0; p < 5; ++p) {
            const float* nW = nullptr;
            if (p < 4) nW = Wg + (p+1)*PFL;
            else if (ol < 2) nW = Wow + (ol+1)*40000;
            if (nW) stage_panel(nW, WowClamp, &Wlds[((par+p+1)&1)*PBUFF], w, lane);
            if (act)
                gemm_panel5(bufA, &Wlds[((par+p)&1)*PBUFF], p*40, kg, r0, n0, sw, acc);
            if (p == 4 && act && kg) {
                #pragma unroll
                for (int i = 0; i < 4; ++i)
                    *(float4*)&bufP[swz(r0+i, n0)] = acc[i];
            }
            __syncthreads();
        }
        par ^= 1;
        if (act && !kg) {
            const float4 b4 = *(const float4*)&Wob[ol*DIMN + n0];
            float4 sc4;
            if (ol == 0) { sc4 = *(const float4*)&scale_s[r0]; }
            else         { sc4.x = sc4.y = sc4.z = sc4.w = 1.f; }
            CMB(0, sc4.x); CMB(1, sc4.y); CMB(2, sc4.z); CMB(3, sc4.w);
        }
        __syncthreads();
    }

    // ---- molecule sum + adduct concat (d2s reused for mv buffers) ----
    float* mv0 = d2s;
    float* mv1 = d2s + 256;
    if (t < DIMN) {
        float s = 0.f;
        #pragma unroll 4
        for (int r = 0; r < 32; ++r)
            s += bufA[(r << 8) + (t ^ (((r >> 2) & 7) << 2))];
        mv0[t] = s;
    } else if (t < DPD) {
        mv0[t] = adducts[mol*4 + (t - 200)];
    }
    __syncthreads();

    // ---- 3 pred layers on [204] vector ----
    float* pc = mv0;
    float* pn = mv1;
    for (int l = 0; l < 3; ++l) {
        if (t < DPD) {
            float acc = Wpb[l*DPD + t];
            const float* Wl = Wpw + l*DPD*DPD;
            #pragma unroll 4
            for (int k = 0; k < DPD; ++k)
                acc = fmaf(pc[k], Wl[k*DPD + t], acc);
            pn[t] = fmaxf(acc, 0.f);
        }
        __syncthreads();
        float* tp = pc; pc = pn; pn = tp;
    }

    // ---- final property head ----
    float v = (t < DPD) ? pc[t] * Wprw[t] : 0.f;
    #pragma unroll
    for (int m = 1; m < 64; m <<= 1) v += __shfl_xor(v, m);
    if (lane == 0) red16[w] = v;
    __syncthreads();
    if (t == 0) {
        float s = Wprb[0];
        #pragma unroll
        for (int ww = 0; ww < 14; ++ww) s += red16[ww];
        out[mol] = s;
    }
}

extern "C" void kernel_launch(void* const* d_in, const int* in_sizes, int n_in,
                              void* d_out, int out_size, void* d_ws, size_t ws_size,
                              hipStream_t stream) {
    const int*   atoms   = (const int*)  d_in[0];
    const float* dist    = (const float*)d_in[1];
    const float* adducts = (const float*)d_in[2];
    const float* embed   = (const float*)d_in[3];
    const float* gamma_t = (const float*)d_in[4];
    const float* Waw     = (const float*)d_in[5];
    const float* Wab     = (const float*)d_in[6];
    const float* Wow     = (const float*)d_in[7];
    const float* Wob     = (const float*)d_in[8];
    const float* Wpw     = (const float*)d_in[9];
    const float* Wpb     = (const float*)d_in[10];
    const float* Wprw    = (const float*)d_in[11];
    const float* Wprb    = (const float*)d_in[12];
    (void)in_sizes; (void)n_in; (void)d_ws; (void)ws_size; (void)out_size;

    mgnn_kernel<<<dim3(256), dim3(896), 0, stream>>>(
        atoms, dist, adducts, embed, gamma_t,
        Waw, Wab, Wow, Wob, Wpw, Wpb, Wprw, Wprb,
        (float*)d_out);
}

// Round 10
// 506.583 us; speedup vs baseline: 1.0974x; 1.0276x over previous
//
#include <hip/hip_runtime.h>
#include <cmath>

// Problem constants
#define NVOC 100
#define DIMN 200
#define LDA  256      // swizzled LDS stride for x/hv rows
#define DPD  204      // DIM + NADD
#define LDM  36       // stride for 32x32 LDS matrices
#define NTOT 8192
// grid = 256 molecules (1 block/CU), block = 896 = 14 waves.
// K-split: kg = w>=7 (k 0..99 | 100..199), wc = col block. Thread tile 4r x 4c.
// R8 structure (deferred norm, 3 barriers/layer, Mts on waves 6..13) + ROTATED
// K-ORDER: wave w starts its 25 k-quads at ((mol>>3) + 2w) % 25 and wraps, so
// XCD-peer CUs and same-CU waves never demand the same W lines simultaneously
// (anti-convoy; bytes unchanged, fp32 k-sum reorder only).

#define FMA4(acc, s, wv) do { \
    (acc).x = fmaf((s),(wv).x,(acc).x); \
    (acc).y = fmaf((s),(wv).y,(acc).y); \
    (acc).z = fmaf((s),(wv).z,(acc).z); \
    (acc).w = fmaf((s),(wv).w,(acc).w); } while(0)

// XOR swizzle: dword col c of row r lives at r*LDA + (c ^ 4*(r>>2)).
__device__ __forceinline__ int swz(int r, int c) {
    return (r << 8) + (c ^ (((r >> 2) & 7) << 2));
}

#define FMA_BLK() do { \
    FMA4(acc[0],a0.x,w0); FMA4(acc[1],a1.x,w0); FMA4(acc[2],a2.x,w0); FMA4(acc[3],a3.x,w0); \
    FMA4(acc[0],a0.y,w1); FMA4(acc[1],a1.y,w1); FMA4(acc[2],a2.y,w1); FMA4(acc[3],a3.y,w1); \
    FMA4(acc[0],a0.z,w2); FMA4(acc[1],a1.z,w2); FMA4(acc[2],a2.z,w2); FMA4(acc[3],a3.z,w2); \
    FMA4(acc[0],a0.w,w3); FMA4(acc[1],a1.w,w3); FMA4(acc[2],a2.w,w3); FMA4(acc[3],a3.w,w3); } while(0)

// Half-K GEMM, zero-init (bias/scale deferred to combine), rotated k-order.
__device__ __forceinline__ void gemm_half(const float* src,
                                          const float* __restrict__ Wg,
                                          int kbase, int koff, int r0, int n0,
                                          int sw, float4 acc[4])
{
    acc[0].x = acc[0].y = acc[0].z = acc[0].w = 0.f;
    acc[1] = acc[0]; acc[2] = acc[0]; acc[3] = acc[0];
    #pragma unroll 5
    for (int i = 0; i < 25; ++i) {
        int j = i + koff; if (j >= 25) j -= 25;   // rotated k-quad index
        const int k0 = kbase + j * 4;
        const int ks = k0 ^ sw;
        const float4 a0 = *(const float4*)&src[(r0+0)*LDA + ks];
        const float4 a1 = *(const float4*)&src[(r0+1)*LDA + ks];
        const float4 a2 = *(const float4*)&src[(r0+2)*LDA + ks];
        const float4 a3 = *(const float4*)&src[(r0+3)*LDA + ks];
        const float* Wk = Wg + k0*DIMN + n0;
        const float4 w0 = *(const float4*)(Wk);
        const float4 w1 = *(const float4*)(Wk + DIMN);
        const float4 w2 = *(const float4*)(Wk + 2*DIMN);
        const float4 w3 = *(const float4*)(Wk + 3*DIMN);
        FMA_BLK();
    }
}

// combine: acc[i] = relu((acc[i] + bufP[i]) * SR + b4), write to bufA
#define CMB(i, SR) do { \
    const float4 pp = *(const float4*)&bufP[swz(r0+i, n0)]; \
    acc[i].x = fmaxf(fmaf(acc[i].x + pp.x, (SR), b4.x), 0.f); \
    acc[i].y = fmaxf(fmaf(acc[i].y + pp.y, (SR), b4.y), 0.f); \
    acc[i].z = fmaxf(fmaf(acc[i].z + pp.z, (SR), b4.z), 0.f); \
    acc[i].w = fmaxf(fmaf(acc[i].w + pp.w, (SR), b4.w), 0.f); \
    *(float4*)&bufA[swz(r0+i, n0)] = acc[i]; } while(0)

__global__ __launch_bounds__(896)
void mgnn_kernel(const int*   __restrict__ atoms,
                 const float* __restrict__ dist,
                 const float* __restrict__ adducts,
                 const float* __restrict__ embed,
                 const float* __restrict__ gamma_tab,
                 const float* __restrict__ Waw,
                 const float* __restrict__ Wab,
                 const float* __restrict__ Wow,
                 const float* __restrict__ Wob,
                 const float* __restrict__ Wpw,
                 const float* __restrict__ Wpb,
                 const float* __restrict__ Wprw,
                 const float* __restrict__ Wprb,
                 float* __restrict__ out)
{
    __shared__ float  bufA[32*LDA];   // x / hv, swizzled (32 KB)
    __shared__ float  bufP[32*LDA];   // k-half-1 partials (32 KB)
    __shared__ float  d2s [32*LDM];
    __shared__ float  Mts [32*LDM];   // Mts[j][r] = M[r][j]
    __shared__ float4 part4[64];      // norm partials [wc][rq]
    __shared__ float  scale_s[32];
    __shared__ float  red16[16];
    __shared__ int    atom_s[32];

    const int mol  = blockIdx.x;
    const int t    = threadIdx.x;
    const int base = mol * 32;
    const int w    = t >> 6;          // wave 0..13
    const int lane = t & 63;
    const int kg   = (w >= 7);
    const int wc   = kg ? (w - 7) : w;
    const int c8   = lane & 7;
    const int rq   = lane >> 3;
    const int r0   = rq * 4;
    const int n0   = wc * 32 + c8 * 4;
    const bool act = (n0 < DIMN);
    const int sw   = (rq & 7) << 2;
    const int kbase = kg ? 100 : 0;
    const int koff  = ((mol >> 3) + 2 * w) % 25;   // anti-convoy rotation

    // ---- init ----
    if (t < 32) atom_s[t] = atoms[base + t];
    if (t < 512) {
        const int j  = t >> 4;
        const int c2 = (t & 15) * 2;
        const float2 dd = *(const float2*)&dist[(size_t)(base + j) * NTOT + base + c2];
        float2 q; q.x = dd.x*dd.x; q.y = dd.y*dd.y;
        *(float2*)&d2s[j*LDM + c2] = q;
    }
    for (int idx = t; idx < 32*50; idx += 896) {
        const int r  = idx / 50;
        const int c4 = (idx % 50) * 4;
        const int a  = atoms[base + r];
        *(float4*)&bufA[swz(r, c4)] = *(const float4*)&embed[a*DIMN + c4];
    }
    __syncthreads();

    // ---- 6 hidden layers (bufA holds UNNORMALIZED x; scale folded forward) ----
    for (int l = 0; l < 6; ++l) {
        float4 acc[4];
        if (act)
            gemm_half(bufA, Waw + l*40000, kbase, koff, r0, n0, sw, acc);
        if (act && kg) {
            #pragma unroll
            for (int i = 0; i < 4; ++i)
                *(float4*)&bufP[swz(r0+i, n0)] = acc[i];
        }
        __syncthreads();   // B0: partials visible; GEMM reads of bufA done

        if (act && !kg) {  // combine on waves 0..6: hv = relu((g0+g1)*s_prev + b)
            const float4 b4 = *(const float4*)&Wab[l*DIMN + n0];
            float4 sc4;
            if (l == 0) { sc4.x = sc4.y = sc4.z = sc4.w = 1.f; }
            else        { sc4 = *(const float4*)&scale_s[r0]; }
            CMB(0, sc4.x); CMB(1, sc4.y); CMB(2, sc4.z); CMB(3, sc4.w);
        }
        if (t >= 384) {    // Mts on waves 6..13 (overlaps combine)
            const int tm = t - 384;
            const int j  = tm >> 4;
            const int rr = (tm & 15) * 2;
            const float g = gamma_tab[l*NVOC + atom_s[j]];
            const float2 d = *(const float2*)&d2s[j*LDM + rr];
            Mts[j*LDM + rr]     = expf(-g*d.x);
            Mts[j*LDM + rr + 1] = expf(-g*d.y);
        }
        __syncthreads();   // B2: hv + Mts visible

        float4 p4; p4.x = p4.y = p4.z = p4.w = 0.f;
        if (act && !kg) {
            // x_next = hv + M@hv (acc holds this thread's hv tile)
            #pragma unroll 4
            for (int jj = 0; jj < 32; ++jj) {
                const float4 m4 = *(const float4*)&Mts[jj*LDM + r0];
                const float4 h4 = *(const float4*)&bufA[swz(jj, n0)];
                FMA4(acc[0], m4.x, h4);
                FMA4(acc[1], m4.y, h4);
                FMA4(acc[2], m4.z, h4);
                FMA4(acc[3], m4.w, h4);
            }
            p4.x = acc[0].x*acc[0].x; p4.x = fmaf(acc[0].y,acc[0].y,p4.x);
            p4.x = fmaf(acc[0].z,acc[0].z,p4.x); p4.x = fmaf(acc[0].w,acc[0].w,p4.x);
            p4.y = acc[1].x*acc[1].x; p4.y = fmaf(acc[1].y,acc[1].y,p4.y);
            p4.y = fmaf(acc[1].z,acc[1].z,p4.y); p4.y = fmaf(acc[1].w,acc[1].w,p4.y);
            p4.z = acc[2].x*acc[2].x; p4.z = fmaf(acc[2].y,acc[2].y,p4.z);
            p4.z = fmaf(acc[2].z,acc[2].z,p4.z); p4.z = fmaf(acc[2].w,acc[2].w,p4.z);
            p4.w = acc[3].x*acc[3].x; p4.w = fmaf(acc[3].y,acc[3].y,p4.w);
            p4.w = fmaf(acc[3].z,acc[3].z,p4.w); p4.w = fmaf(acc[3].w,acc[3].w,p4.w);
        }
        #pragma unroll
        for (int m = 1; m < 8; m <<= 1) {
            p4.x += __shfl_xor(p4.x, m);
            p4.y += __shfl_xor(p4.y, m);
            p4.z += __shfl_xor(p4.z, m);
            p4.w += __shfl_xor(p4.w, m);
        }
        if (act && !kg && c8 == 0) part4[wc*8 + rq] = p4;
        if (act && !kg) {
            #pragma unroll
            for (int i = 0; i < 4; ++i)
                *(float4*)&bufA[swz(r0+i, n0)] = acc[i];   // UNNORMALIZED x
        }
        __syncthreads();   // B3: x + part4 visible
        if (t < 32) {      // scale consumed after next layer's B0
            const float* pf = (const float*)part4;
            const int rqq = t >> 2, cm = t & 3;
            float s = 0.f;
            #pragma unroll
            for (int ww = 0; ww < 7; ++ww) s += pf[((ww*8 + rqq) << 2) + cm];
            scale_s[t] = 1.0f / fmaxf(sqrtf(s), 1e-12f);
        }
    }

    // ---- 3 out layers (deferred scale applied only in the first) ----
    for (int ol = 0; ol < 3; ++ol) {
        float4 acc[4];
        if (act)
            gemm_half(bufA, Wow + ol*40000, kbase, koff, r0, n0, sw, acc);
        if (act && kg) {
            #pragma unroll
            for (int i = 0; i < 4; ++i)
                *(float4*)&bufP[swz(r0+i, n0)] = acc[i];
        }
        __syncthreads();
        if (act && !kg) {
            const float4 b4 = *(const float4*)&Wob[ol*DIMN + n0];
            float4 sc4;
            if (ol == 0) { sc4 = *(const float4*)&scale_s[r0]; }
            else         { sc4.x = sc4.y = sc4.z = sc4.w = 1.f; }
            CMB(0, sc4.x); CMB(1, sc4.y); CMB(2, sc4.z); CMB(3, sc4.w);
        }
        __syncthreads();
    }

    // ---- molecule sum + adduct concat (d2s reused for mv buffers) ----
    float* mv0 = d2s;
    float* mv1 = d2s + 256;
    if (t < DIMN) {
        float s = 0.f;
        #pragma unroll 4
        for (int r = 0; r < 32; ++r)
            s += bufA[(r << 8) + (t ^ (((r >> 2) & 7) << 2))];
        mv0[t] = s;
    } else if (t < DPD) {
        mv0[t] = adducts[mol*4 + (t - 200)];
    }
    __syncthreads();

    // ---- 3 pred layers on [204] vector ----
    float* pc = mv0;
    float* pn = mv1;
    for (int l = 0; l < 3; ++l) {
        if (t < DPD) {
            float acc = Wpb[l*DPD + t];
            const float* Wl = Wpw + l*DPD*DPD;
            #pragma unroll 4
            for (int k = 0; k < DPD; ++k)
                acc = fmaf(pc[k], Wl[k*DPD + t], acc);
            pn[t] = fmaxf(acc, 0.f);
        }
        __syncthreads();
        float* tp = pc; pc = pn; pn = tp;
    }

    // ---- final property head ----
    float v = (t < DPD) ? pc[t] * Wprw[t] : 0.f;
    #pragma unroll
    for (int m = 1; m < 64; m <<= 1) v += __shfl_xor(v, m);
    if (lane == 0) red16[w] = v;
    __syncthreads();
    if (t == 0) {
        float s = Wprb[0];
        #pragma unroll
        for (int ww = 0; ww < 14; ++ww) s += red16[ww];
        out[mol] = s;
    }
}

extern "C" void kernel_launch(void* const* d_in, const int* in_sizes, int n_in,
                              void* d_out, int out_size, void* d_ws, size_t ws_size,
                              hipStream_t stream) {
    const int*   atoms   = (const int*)  d_in[0];
    const float* dist    = (const float*)d_in[1];
    const float* adducts = (const float*)d_in[2];
    const float* embed   = (const float*)d_in[3];
    const float* gamma_t = (const float*)d_in[4];
    const float* Waw     = (const float*)d_in[5];
    const float* Wab     = (const float*)d_in[6];
    const float* Wow     = (const float*)d_in[7];
    const float* Wob     = (const float*)d_in[8];
    const float* Wpw     = (const float*)d_in[9];
    const float* Wpb     = (const float*)d_in[10];
    const float* Wprw    = (const float*)d_in[11];
    const float* Wprb    = (const float*)d_in[12];
    (void)in_sizes; (void)n_in; (void)d_ws; (void)ws_size; (void)out_size;

    mgnn_kernel<<<dim3(256), dim3(896), 0, stream>>>(
        atoms, dist, adducts, embed, gamma_t,
        Waw, Wab, Wow, Wob, Wpw, Wpb, Wprw, Wprb,
        (float*)d_out);
}

// Round 11
// 441.704 us; speedup vs baseline: 1.2585x; 1.1469x over previous
//
#include <hip/hip_runtime.h>
#include <hip/hip_bf16.h>
#include <cmath>

// Problem constants
#define NVOC 100
#define DIMN 200
#define LDA  256      // swizzled fp32 bufA stride (dwords)
#define LDS_S 212     // bufS (raw GEMM sums) stride (dwords)
#define LDX  232      // xHi/xLo stride (bf16 elems); 232*2B=464B -> conflict-free frags
#define DPD  204
#define LDM  36
#define NTOT 8192
#define KP   224      // K padded to 7*32
#define NP   208      // N padded to 13*16
#define WHALF (NP*KP) // bf16 elems per half (hi or lo) per layer
#define WL    (2*WHALF)
// grid = 256 molecules (1 block/CU), block = 832 = 13 waves (one 16-col ntile each).
// GEMM via mfma_f32_16x16x32_bf16 with split-bf16 (hi/lo) for fp32 accuracy:
// C = xhi*Whi + xhi*Wlo + xlo*Whi. W pre-converted by conv_kernel into d_ws as
// [layer][hi/lo][n][k] bf16 (transposed so each lane's 8 k-elems are contiguous;
// each global B-frag load = 16 fully-used 64B lines).

typedef __attribute__((ext_vector_type(8))) short short8_t;
typedef __attribute__((ext_vector_type(4))) short short4_t;
typedef __attribute__((ext_vector_type(4))) float f32x4;

__device__ __forceinline__ short f2bf(float v) {
    __hip_bfloat16 h = __float2bfloat16(v);
    return *reinterpret_cast<short*>(&h);
}
__device__ __forceinline__ float bf2f(short s) {
    __hip_bfloat16 h = *reinterpret_cast<__hip_bfloat16*>(&s);
    return __bfloat162float(h);
}

#define FMA4(acc, s, wv) do { \
    (acc).x = fmaf((s),(wv).x,(acc).x); \
    (acc).y = fmaf((s),(wv).y,(acc).y); \
    (acc).z = fmaf((s),(wv).z,(acc).z); \
    (acc).w = fmaf((s),(wv).w,(acc).w); } while(0)

// XOR swizzle for fp32 bufA: dword col c of row r at r*LDA + (c ^ 4*(r>>2)).
__device__ __forceinline__ int swz(int r, int c) {
    return (r << 8) + (c ^ (((r >> 2) & 7) << 2));
}

// ---- W conversion pre-pass: fp32 [k][n] -> bf16 hi/lo [n][k], padded ----
__global__ void conv_kernel(const float* __restrict__ Waw,
                            const float* __restrict__ Wow,
                            short* __restrict__ W2)
{
    const int total = 9 * NP * KP;
    for (int idx = blockIdx.x * 256 + threadIdx.x; idx < total;
         idx += gridDim.x * 256) {
        const int l = idx / (NP*KP);
        const int rem = idx % (NP*KP);
        const int n = rem / KP;
        const int k = rem % KP;
        float v = 0.f;
        if (n < DIMN && k < DIMN)
            v = (l < 6) ? Waw[l*40000 + k*DIMN + n]
                        : Wow[(l-6)*40000 + k*DIMN + n];
        const short hi = f2bf(v);
        const short lo = f2bf(v - bf2f(hi));
        W2[(size_t)l*WL + n*KP + k]         = hi;
        W2[(size_t)l*WL + WHALF + n*KP + k] = lo;
    }
}

// MFMA GEMM: wave w computes cols 16w..16w+15, both 16-row M-tiles, full K.
__device__ __forceinline__ void gemm_mfma(const short* __restrict__ xHi,
                                          const short* __restrict__ xLo,
                                          const short* __restrict__ Wl,
                                          int w, int lane, f32x4 acc[2])
{
    acc[0] = (f32x4){0.f,0.f,0.f,0.f};
    acc[1] = (f32x4){0.f,0.f,0.f,0.f};
    const int m = lane & 15;
    const int q = lane >> 4;
    const short* aH0 = xHi + m*LDX + q*8;
    const short* aL0 = xLo + m*LDX + q*8;
    const short* aH1 = aH0 + 16*LDX;
    const short* aL1 = aL0 + 16*LDX;
    const short* bH  = Wl + (w*16 + m)*KP + q*8;
    const short* bL  = bH + WHALF;
    #pragma unroll
    for (int ks = 0; ks < 7; ++ks) {
        const int ko = ks * 32;
        const short8_t ah0 = *(const short8_t*)(aH0 + ko);
        const short8_t al0 = *(const short8_t*)(aL0 + ko);
        const short8_t ah1 = *(const short8_t*)(aH1 + ko);
        const short8_t al1 = *(const short8_t*)(aL1 + ko);
        const short8_t bh  = *(const short8_t*)(bH + ko);
        const short8_t bl  = *(const short8_t*)(bL + ko);
        acc[0] = __builtin_amdgcn_mfma_f32_16x16x32_bf16(ah0, bh, acc[0], 0,0,0);
        acc[0] = __builtin_amdgcn_mfma_f32_16x16x32_bf16(ah0, bl, acc[0], 0,0,0);
        acc[0] = __builtin_amdgcn_mfma_f32_16x16x32_bf16(al0, bh, acc[0], 0,0,0);
        acc[1] = __builtin_amdgcn_mfma_f32_16x16x32_bf16(ah1, bh, acc[1], 0,0,0);
        acc[1] = __builtin_amdgcn_mfma_f32_16x16x32_bf16(ah1, bl, acc[1], 0,0,0);
        acc[1] = __builtin_amdgcn_mfma_f32_16x16x32_bf16(al1, bh, acc[1], 0,0,0);
    }
}

__global__ __launch_bounds__(832)
void mgnn_kernel(const int*   __restrict__ atoms,
                 const float* __restrict__ dist,
                 const float* __restrict__ adducts,
                 const float* __restrict__ embed,
                 const float* __restrict__ gamma_tab,
                 const float* __restrict__ Waw,
                 const float* __restrict__ Wab,
                 const float* __restrict__ Wow,
                 const float* __restrict__ Wob,
                 const float* __restrict__ Wpw,
                 const float* __restrict__ Wpb,
                 const float* __restrict__ Wprw,
                 const float* __restrict__ Wprb,
                 const short* __restrict__ W2,
                 float* __restrict__ out)
{
    __shared__ float bufA[32*LDA];    // hv / av fp32, swizzled (32 KB)
    __shared__ float bufS[32*LDS_S];  // raw GEMM sums fp32 (27 KB)
    __shared__ short xHi[32*LDX];     // x high bf16 (14.8 KB)
    __shared__ short xLo[32*LDX];     // x low  bf16 (14.8 KB)
    __shared__ float d2s[32*LDM];
    __shared__ float Mts[32*LDM];     // Mts[j][r] = M[r][j]
    __shared__ float4 part4[64];
    __shared__ float scale_s[32];
    __shared__ float red16[16];
    __shared__ int   atom_s[32];
    // total ~100 KB

    const int mol  = blockIdx.x;
    const int t    = threadIdx.x;
    const int base = mol * 32;
    const int w    = t >> 6;          // wave 0..12 = ntile
    const int lane = t & 63;
    // epilogue mapping (waves 0..6): 4r x 4c per thread
    const int c8   = lane & 7;
    const int rq   = lane >> 3;
    const int r0   = rq * 4;
    const int n0   = w * 32 + c8 * 4;
    const bool act = (n0 < DIMN);     // false for all of waves 7..12

    // ---- init ----
    if (t < 32) atom_s[t] = atoms[base + t];
    if (t < 512) {
        const int j  = t >> 4;
        const int c2 = (t & 15) * 2;
        const float2 dd = *(const float2*)&dist[(size_t)(base + j) * NTOT + base + c2];
        d2s[j*LDM + c2]     = dd.x * dd.x;
        d2s[j*LDM + c2 + 1] = dd.y * dd.y;
    }
    for (int idx = t; idx < 32*DIMN; idx += 832) {   // x0 = embed[atoms], split
        const int r = idx / DIMN, c = idx % DIMN;
        const float v = embed[atoms[base + r]*DIMN + c];
        const short hi = f2bf(v);
        xHi[r*LDX + c] = hi;
        xLo[r*LDX + c] = f2bf(v - bf2f(hi));
    }
    for (int idx = t; idx < 32*32; idx += 832) {     // zero k-pad 200..231
        const int r = idx >> 5, c = DIMN + (idx & 31);
        xHi[r*LDX + c] = 0;
        xLo[r*LDX + c] = 0;
    }
    __syncthreads();

    // ---- 6 hidden layers (x stored UNNORMALIZED as bf16 hi/lo; scale folded) ----
    for (int l = 0; l < 6; ++l) {
        f32x4 macc[2];
        gemm_mfma(xHi, xLo, W2 + (size_t)l*WL, w, lane, macc);
        {   // raw sums -> bufS: row = q*4+i (+16), col = 16w + m
            const int col = w*16 + (lane & 15);
            const int q   = lane >> 4;
            #pragma unroll
            for (int i = 0; i < 4; ++i) {
                bufS[(q*4+i)*LDS_S + col]      = macc[0][i];
                bufS[(q*4+i+16)*LDS_S + col]   = macc[1][i];
            }
        }
        __syncthreads();   // B0: sums visible

        float4 acc[4];
        if (act) {         // combine: hv = relu(sum*s_prev + b)
            const float4 b4 = *(const float4*)&Wab[l*DIMN + n0];
            float4 sc4;
            if (l == 0) { sc4.x = sc4.y = sc4.z = sc4.w = 1.f; }
            else        { sc4 = *(const float4*)&scale_s[r0]; }
            const float sra[4] = {sc4.x, sc4.y, sc4.z, sc4.w};
            #pragma unroll
            for (int i = 0; i < 4; ++i) {
                const float4 s4 = *(const float4*)&bufS[(r0+i)*LDS_S + n0];
                acc[i].x = fmaxf(fmaf(s4.x, sra[i], b4.x), 0.f);
                acc[i].y = fmaxf(fmaf(s4.y, sra[i], b4.y), 0.f);
                acc[i].z = fmaxf(fmaf(s4.z, sra[i], b4.z), 0.f);
                acc[i].w = fmaxf(fmaf(s4.w, sra[i], b4.w), 0.f);
                *(float4*)&bufA[swz(r0+i, n0)] = acc[i];   // hv
            }
        }
        if (t >= 448) {    // Mts on waves 7..12 (overlaps combine)
            const int tm = t - 448;
            for (int idx = tm; idx < 1024; idx += 384) {
                const int j = idx >> 5, rr = idx & 31;
                const float g = gamma_tab[l*NVOC + atom_s[j]];
                Mts[j*LDM + rr] = expf(-g * d2s[j*LDM + rr]);
            }
        }
        __syncthreads();   // B2: hv + Mts visible

        float4 p4; p4.x = p4.y = p4.z = p4.w = 0.f;
        if (act) {
            // x_next = hv + M@hv (acc holds this thread's hv tile)
            #pragma unroll 4
            for (int jj = 0; jj < 32; ++jj) {
                const float4 m4 = *(const float4*)&Mts[jj*LDM + r0];
                const float4 h4 = *(const float4*)&bufA[swz(jj, n0)];
                FMA4(acc[0], m4.x, h4);
                FMA4(acc[1], m4.y, h4);
                FMA4(acc[2], m4.z, h4);
                FMA4(acc[3], m4.w, h4);
            }
            p4.x = acc[0].x*acc[0].x; p4.x = fmaf(acc[0].y,acc[0].y,p4.x);
            p4.x = fmaf(acc[0].z,acc[0].z,p4.x); p4.x = fmaf(acc[0].w,acc[0].w,p4.x);
            p4.y = acc[1].x*acc[1].x; p4.y = fmaf(acc[1].y,acc[1].y,p4.y);
            p4.y = fmaf(acc[1].z,acc[1].z,p4.y); p4.y = fmaf(acc[1].w,acc[1].w,p4.y);
            p4.z = acc[2].x*acc[2].x; p4.z = fmaf(acc[2].y,acc[2].y,p4.z);
            p4.z = fmaf(acc[2].z,acc[2].z,p4.z); p4.z = fmaf(acc[2].w,acc[2].w,p4.z);
            p4.w = acc[3].x*acc[3].x; p4.w = fmaf(acc[3].y,acc[3].y,p4.w);
            p4.w = fmaf(acc[3].z,acc[3].z,p4.w); p4.w = fmaf(acc[3].w,acc[3].w,p4.w);
            // split x -> bf16 hi/lo for next layer's GEMM
            #pragma unroll
            for (int i = 0; i < 4; ++i) {
                const int row = r0 + i;
                const float vv[4] = {acc[i].x, acc[i].y, acc[i].z, acc[i].w};
                short4_t h4s, l4s;
                #pragma unroll
                for (int c = 0; c < 4; ++c) {
                    const short hb = f2bf(vv[c]);
                    h4s[c] = hb;
                    l4s[c] = f2bf(vv[c] - bf2f(hb));
                }
                *(short4_t*)&xHi[row*LDX + n0] = h4s;
                *(short4_t*)&xLo[row*LDX + n0] = l4s;
            }
        }
        #pragma unroll
        for (int m = 1; m < 8; m <<= 1) {
            p4.x += __shfl_xor(p4.x, m);
            p4.y += __shfl_xor(p4.y, m);
            p4.z += __shfl_xor(p4.z, m);
            p4.w += __shfl_xor(p4.w, m);
        }
        if (act && c8 == 0) part4[w*8 + rq] = p4;
        __syncthreads();   // B3: x (bf16) + part4 visible
        if (t < 32) {      // scale consumed in next combine
            const float* pf = (const float*)part4;
            const int rqq = t >> 2, cm = t & 3;
            float s = 0.f;
            #pragma unroll
            for (int ww = 0; ww < 7; ++ww) s += pf[((ww*8 + rqq) << 2) + cm];
            scale_s[t] = 1.0f / fmaxf(sqrtf(s), 1e-12f);
        }
    }

    // ---- 3 out layers (deferred scale only in the first) ----
    for (int ol = 0; ol < 3; ++ol) {
        f32x4 macc[2];
        gemm_mfma(xHi, xLo, W2 + (size_t)(6+ol)*WL, w, lane, macc);
        {
            const int col = w*16 + (lane & 15);
            const int q   = lane >> 4;
            #pragma unroll
            for (int i = 0; i < 4; ++i) {
                bufS[(q*4+i)*LDS_S + col]    = macc[0][i];
                bufS[(q*4+i+16)*LDS_S + col] = macc[1][i];
            }
        }
        __syncthreads();
        if (act) {
            const float4 b4 = *(const float4*)&Wob[ol*DIMN + n0];
            float4 sc4;
            if (ol == 0) { sc4 = *(const float4*)&scale_s[r0]; }
            else         { sc4.x = sc4.y = sc4.z = sc4.w = 1.f; }
            const float sra[4] = {sc4.x, sc4.y, sc4.z, sc4.w};
            #pragma unroll
            for (int i = 0; i < 4; ++i) {
                const float4 s4 = *(const float4*)&bufS[(r0+i)*LDS_S + n0];
                float4 av;
                av.x = fmaxf(fmaf(s4.x, sra[i], b4.x), 0.f);
                av.y = fmaxf(fmaf(s4.y, sra[i], b4.y), 0.f);
                av.z = fmaxf(fmaf(s4.z, sra[i], b4.z), 0.f);
                av.w = fmaxf(fmaf(s4.w, sra[i], b4.w), 0.f);
                *(float4*)&bufA[swz(r0+i, n0)] = av;
                const int row = r0 + i;
                const float vv[4] = {av.x, av.y, av.z, av.w};
                short4_t h4s, l4s;
                #pragma unroll
                for (int c = 0; c < 4; ++c) {
                    const short hb = f2bf(vv[c]);
                    h4s[c] = hb;
                    l4s[c] = f2bf(vv[c] - bf2f(hb));
                }
                *(short4_t*)&xHi[row*LDX + n0] = h4s;
                *(short4_t*)&xLo[row*LDX + n0] = l4s;
            }
        }
        __syncthreads();
    }

    // ---- molecule sum + adduct concat (d2s reused for mv buffers) ----
    float* mv0 = d2s;
    float* mv1 = d2s + 256;
    if (t < DIMN) {
        float s = 0.f;
        #pragma unroll 4
        for (int r = 0; r < 32; ++r)
            s += bufA[(r << 8) + (t ^ (((r >> 2) & 7) << 2))];
        mv0[t] = s;
    } else if (t < DPD) {
        mv0[t] = adducts[mol*4 + (t - 200)];
    }
    __syncthreads();

    // ---- 3 pred layers on [204] vector ----
    float* pc = mv0;
    float* pn = mv1;
    for (int l = 0; l < 3; ++l) {
        if (t < DPD) {
            float acc = Wpb[l*DPD + t];
            const float* Wl = Wpw + l*DPD*DPD;
            #pragma unroll 4
            for (int k = 0; k < DPD; ++k)
                acc = fmaf(pc[k], Wl[k*DPD + t], acc);
            pn[t] = fmaxf(acc, 0.f);
        }
        __syncthreads();
        float* tp = pc; pc = pn; pn = tp;
    }

    // ---- final property head ----
    float v = (t < DPD) ? pc[t] * Wprw[t] : 0.f;
    #pragma unroll
    for (int m = 1; m < 64; m <<= 1) v += __shfl_xor(v, m);
    if (lane == 0) red16[w] = v;
    __syncthreads();
    if (t == 0) {
        float s = Wprb[0];
        #pragma unroll
        for (int ww = 0; ww < 13; ++ww) s += red16[ww];
        out[mol] = s;
    }
}

extern "C" void kernel_launch(void* const* d_in, const int* in_sizes, int n_in,
                              void* d_out, int out_size, void* d_ws, size_t ws_size,
                              hipStream_t stream) {
    const int*   atoms   = (const int*)  d_in[0];
    const float* dist    = (const float*)d_in[1];
    const float* adducts = (const float*)d_in[2];
    const float* embed   = (const float*)d_in[3];
    const float* gamma_t = (const float*)d_in[4];
    const float* Waw     = (const float*)d_in[5];
    const float* Wab     = (const float*)d_in[6];
    const float* Wow     = (const float*)d_in[7];
    const float* Wob     = (const float*)d_in[8];
    const float* Wpw     = (const float*)d_in[9];
    const float* Wpb     = (const float*)d_in[10];
    const float* Wprw    = (const float*)d_in[11];
    const float* Wprb    = (const float*)d_in[12];
    (void)in_sizes; (void)n_in; (void)ws_size; (void)out_size;

    short* W2 = (short*)d_ws;   // 9*WL shorts = ~1.68 MB

    conv_kernel<<<dim3(512), dim3(256), 0, stream>>>(Waw, Wow, W2);
    mgnn_kernel<<<dim3(256), dim3(832), 0, stream>>>(
        atoms, dist, adducts, embed, gamma_t,
        Waw, Wab, Wow, Wob, Wpw, Wpb, Wprw, Wprb,
        W2, (float*)d_out);
}

// Round 12
// 438.846 us; speedup vs baseline: 1.2667x; 1.0065x over previous
//
#include <hip/hip_runtime.h>
#include <hip/hip_bf16.h>
#include <cmath>

// Problem constants
#define NVOC 100
#define DIMN 200
#define LDA  256      // swizzled fp32 bufA stride (dwords) — out layers only
#define LDS_S 212     // bufS (raw GEMM sums / P) stride (dwords)
#define LDX  232      // xHi/xLo stride (bf16 elems)
#define LDHT 40       // hvT stride (bf16): hvT[c][j], j=0..31
#define LDMA 40       // MA stride (bf16): MA[r][j], j=0..31
#define DPD  204
#define LDM  36
#define NTOT 8192
#define KP   224      // K padded to 7*32
#define NP   208      // N padded to 13*16
#define WHALF (NP*KP)
#define WL    (2*WHALF)
// grid = 256 (1 block/CU), block = 832 = 13 waves. Both GEMMs (x@W and M@hv)
// run on MFMA with split-bf16 (hi/lo) fp32 accuracy. Hidden layers keep hv in
// registers (combine and x-epilogue are the same thread) — no bufA round-trip.

typedef __attribute__((ext_vector_type(8))) short short8_t;
typedef __attribute__((ext_vector_type(4))) short short4_t;
typedef __attribute__((ext_vector_type(4))) float f32x4;

__device__ __forceinline__ short f2bf(float v) {
    __hip_bfloat16 h = __float2bfloat16(v);
    return *reinterpret_cast<short*>(&h);
}
__device__ __forceinline__ float bf2f(short s) {
    __hip_bfloat16 h = *reinterpret_cast<__hip_bfloat16*>(&s);
    return __bfloat162float(h);
}

// XOR swizzle for fp32 bufA (out layers): dword col c of row r.
__device__ __forceinline__ int swz(int r, int c) {
    return (r << 8) + (c ^ (((r >> 2) & 7) << 2));
}

// ---- W conversion pre-pass: fp32 [k][n] -> bf16 hi/lo [n][k], padded ----
__global__ void conv_kernel(const float* __restrict__ Waw,
                            const float* __restrict__ Wow,
                            short* __restrict__ W2)
{
    const int total = 9 * NP * KP;
    for (int idx = blockIdx.x * 256 + threadIdx.x; idx < total;
         idx += gridDim.x * 256) {
        const int l = idx / (NP*KP);
        const int rem = idx % (NP*KP);
        const int n = rem / KP;
        const int k = rem % KP;
        float v = 0.f;
        if (n < DIMN && k < DIMN)
            v = (l < 6) ? Waw[l*40000 + k*DIMN + n]
                        : Wow[(l-6)*40000 + k*DIMN + n];
        const short hi = f2bf(v);
        const short lo = f2bf(v - bf2f(hi));
        W2[(size_t)l*WL + n*KP + k]         = hi;
        W2[(size_t)l*WL + WHALF + n*KP + k] = lo;
    }
}

// MFMA GEMM: wave w computes cols 16w..16w+15, both 16-row M-tiles, full K.
__device__ __forceinline__ void gemm_mfma(const short* __restrict__ xHi,
                                          const short* __restrict__ xLo,
                                          const short* __restrict__ Wl,
                                          int w, int lane, f32x4 acc[2])
{
    acc[0] = (f32x4){0.f,0.f,0.f,0.f};
    acc[1] = (f32x4){0.f,0.f,0.f,0.f};
    const int m = lane & 15;
    const int q = lane >> 4;
    const short* aH0 = xHi + m*LDX + q*8;
    const short* aL0 = xLo + m*LDX + q*8;
    const short* aH1 = aH0 + 16*LDX;
    const short* aL1 = aL0 + 16*LDX;
    const short* bH  = Wl + (w*16 + m)*KP + q*8;
    const short* bL  = bH + WHALF;
    #pragma unroll
    for (int ks = 0; ks < 7; ++ks) {
        const int ko = ks * 32;
        const short8_t ah0 = *(const short8_t*)(aH0 + ko);
        const short8_t al0 = *(const short8_t*)(aL0 + ko);
        const short8_t ah1 = *(const short8_t*)(aH1 + ko);
        const short8_t al1 = *(const short8_t*)(aL1 + ko);
        const short8_t bh  = *(const short8_t*)(bH + ko);
        const short8_t bl  = *(const short8_t*)(bL + ko);
        acc[0] = __builtin_amdgcn_mfma_f32_16x16x32_bf16(ah0, bh, acc[0], 0,0,0);
        acc[0] = __builtin_amdgcn_mfma_f32_16x16x32_bf16(ah0, bl, acc[0], 0,0,0);
        acc[0] = __builtin_amdgcn_mfma_f32_16x16x32_bf16(al0, bh, acc[0], 0,0,0);
        acc[1] = __builtin_amdgcn_mfma_f32_16x16x32_bf16(ah1, bh, acc[1], 0,0,0);
        acc[1] = __builtin_amdgcn_mfma_f32_16x16x32_bf16(ah1, bl, acc[1], 0,0,0);
        acc[1] = __builtin_amdgcn_mfma_f32_16x16x32_bf16(al1, bh, acc[1], 0,0,0);
    }
}

__global__ __launch_bounds__(832)
void mgnn_kernel(const int*   __restrict__ atoms,
                 const float* __restrict__ dist,
                 const float* __restrict__ adducts,
                 const float* __restrict__ embed,
                 const float* __restrict__ gamma_tab,
                 const float* __restrict__ Waw,
                 const float* __restrict__ Wab,
                 const float* __restrict__ Wow,
                 const float* __restrict__ Wob,
                 const float* __restrict__ Wpw,
                 const float* __restrict__ Wpb,
                 const float* __restrict__ Wprw,
                 const float* __restrict__ Wprb,
                 const short* __restrict__ W2,
                 float* __restrict__ out)
{
    __shared__ float bufA[32*LDA];     // av fp32, swizzled (out layers / mol-sum)
    __shared__ float bufS[32*LDS_S];   // raw GEMM sums / P fp32 (27 KB)
    __shared__ short xHi[32*LDX];      // x high bf16
    __shared__ short xLo[32*LDX];      // x low  bf16
    __shared__ short hvThi[NP*LDHT];   // hv^T high bf16 (B-layout for M@hv)
    __shared__ short hvTlo[NP*LDHT];   // hv^T low
    __shared__ short MAhi[32*LDMA];    // M high bf16 (A-layout)
    __shared__ short MAlo[32*LDMA];    // M low
    __shared__ float d2s[32*LDM];
    __shared__ float4 part4[64];
    __shared__ float scale_s[32];
    __shared__ float red16[16];
    __shared__ int   atom_s[32];
    // total ~131 KB < 160 KB

    const int mol  = blockIdx.x;
    const int t    = threadIdx.x;
    const int base = mol * 32;
    const int w    = t >> 6;          // wave 0..12 = ntile
    const int lane = t & 63;
    const int ml   = lane & 15;
    const int q    = lane >> 4;
    // epilogue mapping (waves 0..6): 4r x 4c per thread
    const int c8   = lane & 7;
    const int rq   = lane >> 3;
    const int r0   = rq * 4;
    const int n0   = w * 32 + c8 * 4;
    const bool act = (n0 < DIMN);

    // ---- init ----
    if (t < 32) atom_s[t] = atoms[base + t];
    if (t < 512) {
        const int j  = t >> 4;
        const int c2 = (t & 15) * 2;
        const float2 dd = *(const float2*)&dist[(size_t)(base + j) * NTOT + base + c2];
        d2s[j*LDM + c2]     = dd.x * dd.x;
        d2s[j*LDM + c2 + 1] = dd.y * dd.y;
    }
    for (int idx = t; idx < 32*DIMN; idx += 832) {   // x0 = embed[atoms], split
        const int r = idx / DIMN, c = idx % DIMN;
        const float v = embed[atoms[base + r]*DIMN + c];
        const short hi = f2bf(v);
        xHi[r*LDX + c] = hi;
        xLo[r*LDX + c] = f2bf(v - bf2f(hi));
    }
    for (int idx = t; idx < 32*32; idx += 832) {     // zero k-pad 200..231
        const int r = idx >> 5, c = DIMN + (idx & 31);
        xHi[r*LDX + c] = 0;
        xLo[r*LDX + c] = 0;
    }
    if (t < 256) {                                   // zero hvT pad rows 200..207
        const int r = NP - 8 + (t >> 5), j = t & 31;
        hvThi[r*LDHT + j] = 0;
        hvTlo[r*LDHT + j] = 0;
    }
    __syncthreads();

    // ---- 6 hidden layers ----
    for (int l = 0; l < 6; ++l) {
        f32x4 macc[2];
        gemm_mfma(xHi, xLo, W2 + (size_t)l*WL, w, lane, macc);
        {   // raw sums -> bufS
            const int col = w*16 + ml;
            #pragma unroll
            for (int i = 0; i < 4; ++i) {
                bufS[(q*4+i)*LDS_S + col]    = macc[0][i];
                bufS[(q*4+i+16)*LDS_S + col] = macc[1][i];
            }
        }
        __syncthreads();   // B0: sums visible

        float4 acc[4];     // hv tile, kept in registers through P phase
        if (act) {         // combine: hv = relu(sum*s_prev + b); write hvT splits
            const float4 b4 = *(const float4*)&Wab[l*DIMN + n0];
            float4 sc4;
            if (l == 0) { sc4.x = sc4.y = sc4.z = sc4.w = 1.f; }
            else        { sc4 = *(const float4*)&scale_s[r0]; }
            const float sra[4] = {sc4.x, sc4.y, sc4.z, sc4.w};
            #pragma unroll
            for (int i = 0; i < 4; ++i) {
                const float4 s4 = *(const float4*)&bufS[(r0+i)*LDS_S + n0];
                acc[i].x = fmaxf(fmaf(s4.x, sra[i], b4.x), 0.f);
                acc[i].y = fmaxf(fmaf(s4.y, sra[i], b4.y), 0.f);
                acc[i].z = fmaxf(fmaf(s4.z, sra[i], b4.z), 0.f);
                acc[i].w = fmaxf(fmaf(s4.w, sra[i], b4.w), 0.f);
            }
            // hvT[c][j] bf16 hi/lo (B-operand layout for M@hv)
            #pragma unroll
            for (int c = 0; c < 4; ++c) {
                const float cv[4] = {
                    c==0?acc[0].x:c==1?acc[0].y:c==2?acc[0].z:acc[0].w,
                    c==0?acc[1].x:c==1?acc[1].y:c==2?acc[1].z:acc[1].w,
                    c==0?acc[2].x:c==1?acc[2].y:c==2?acc[2].z:acc[2].w,
                    c==0?acc[3].x:c==1?acc[3].y:c==2?acc[3].z:acc[3].w };
                short4_t hh, hl;
                #pragma unroll
                for (int i = 0; i < 4; ++i) {
                    const short hb = f2bf(cv[i]);
                    hh[i] = hb;
                    hl[i] = f2bf(cv[i] - bf2f(hb));
                }
                *(short4_t*)&hvThi[(n0+c)*LDHT + r0] = hh;
                *(short4_t*)&hvTlo[(n0+c)*LDHT + r0] = hl;
            }
        }
        if (t >= 448) {    // M bf16 hi/lo in A-layout, waves 7..12
            for (int idx = t - 448; idx < 1024; idx += 384) {
                const int r = idx >> 5, j = idx & 31;
                const float g = gamma_tab[l*NVOC + atom_s[j]];
                const float v = expf(-g * d2s[r*LDM + j]);
                const short hb = f2bf(v);
                MAhi[r*LDMA + j] = hb;
                MAlo[r*LDMA + j] = f2bf(v - bf2f(hb));
            }
        }
        __syncthreads();   // B2: hvT + MA visible

        {   // P = M @ hv via MFMA (K=32, one step), all 13 waves
            const short8_t bh  = *(const short8_t*)&hvThi[(16*w + ml)*LDHT + q*8];
            const short8_t bl  = *(const short8_t*)&hvTlo[(16*w + ml)*LDHT + q*8];
            const short8_t a0h = *(const short8_t*)&MAhi[ml*LDMA + q*8];
            const short8_t a0l = *(const short8_t*)&MAlo[ml*LDMA + q*8];
            const short8_t a1h = *(const short8_t*)&MAhi[(16+ml)*LDMA + q*8];
            const short8_t a1l = *(const short8_t*)&MAlo[(16+ml)*LDMA + q*8];
            f32x4 p0 = (f32x4){0.f,0.f,0.f,0.f};
            f32x4 p1 = (f32x4){0.f,0.f,0.f,0.f};
            p0 = __builtin_amdgcn_mfma_f32_16x16x32_bf16(a0h, bh, p0, 0,0,0);
            p0 = __builtin_amdgcn_mfma_f32_16x16x32_bf16(a0h, bl, p0, 0,0,0);
            p0 = __builtin_amdgcn_mfma_f32_16x16x32_bf16(a0l, bh, p0, 0,0,0);
            p1 = __builtin_amdgcn_mfma_f32_16x16x32_bf16(a1h, bh, p1, 0,0,0);
            p1 = __builtin_amdgcn_mfma_f32_16x16x32_bf16(a1h, bl, p1, 0,0,0);
            p1 = __builtin_amdgcn_mfma_f32_16x16x32_bf16(a1l, bh, p1, 0,0,0);
            const int col = 16*w + ml;
            #pragma unroll
            for (int i = 0; i < 4; ++i) {
                bufS[(q*4+i)*LDS_S + col]    = p0[i];
                bufS[(q*4+i+16)*LDS_S + col] = p1[i];
            }
        }
        __syncthreads();   // B3: P visible

        float4 p4; p4.x = p4.y = p4.z = p4.w = 0.f;
        if (act) {         // x = hv + P; norm partials; bf16 splits
            #pragma unroll
            for (int i = 0; i < 4; ++i) {
                const float4 pp = *(const float4*)&bufS[(r0+i)*LDS_S + n0];
                float4 xv;
                xv.x = acc[i].x + pp.x; xv.y = acc[i].y + pp.y;
                xv.z = acc[i].z + pp.z; xv.w = acc[i].w + pp.w;
                float s = xv.x*xv.x;
                s = fmaf(xv.y, xv.y, s); s = fmaf(xv.z, xv.z, s);
                s = fmaf(xv.w, xv.w, s);
                if (i == 0) p4.x = s; else if (i == 1) p4.y = s;
                else if (i == 2) p4.z = s; else p4.w = s;
                const float vv[4] = {xv.x, xv.y, xv.z, xv.w};
                short4_t h4s, l4s;
                #pragma unroll
                for (int c = 0; c < 4; ++c) {
                    const short hb = f2bf(vv[c]);
                    h4s[c] = hb;
                    l4s[c] = f2bf(vv[c] - bf2f(hb));
                }
                *(short4_t*)&xHi[(r0+i)*LDX + n0] = h4s;
                *(short4_t*)&xLo[(r0+i)*LDX + n0] = l4s;
            }
        }
        #pragma unroll
        for (int m = 1; m < 8; m <<= 1) {
            p4.x += __shfl_xor(p4.x, m);
            p4.y += __shfl_xor(p4.y, m);
            p4.z += __shfl_xor(p4.z, m);
            p4.w += __shfl_xor(p4.w, m);
        }
        if (act && c8 == 0) part4[w*8 + rq] = p4;
        __syncthreads();   // B4: x splits + part4 visible
        if (t < 32) {      // scale consumed in next combine
            const float* pf = (const float*)part4;
            const int rqq = t >> 2, cm = t & 3;
            float s = 0.f;
            #pragma unroll
            for (int ww = 0; ww < 7; ++ww) s += pf[((ww*8 + rqq) << 2) + cm];
            scale_s[t] = 1.0f / fmaxf(sqrtf(s), 1e-12f);
        }
    }

    // ---- 3 out layers (deferred scale only in the first) ----
    for (int ol = 0; ol < 3; ++ol) {
        f32x4 macc[2];
        gemm_mfma(xHi, xLo, W2 + (size_t)(6+ol)*WL, w, lane, macc);
        {
            const int col = w*16 + ml;
            #pragma unroll
            for (int i = 0; i < 4; ++i) {
                bufS[(q*4+i)*LDS_S + col]    = macc[0][i];
                bufS[(q*4+i+16)*LDS_S + col] = macc[1][i];
            }
        }
        __syncthreads();
        if (act) {
            const float4 b4 = *(const float4*)&Wob[ol*DIMN + n0];
            float4 sc4;
            if (ol == 0) { sc4 = *(const float4*)&scale_s[r0]; }
            else         { sc4.x = sc4.y = sc4.z = sc4.w = 1.f; }
            const float sra[4] = {sc4.x, sc4.y, sc4.z, sc4.w};
            #pragma unroll
            for (int i = 0; i < 4; ++i) {
                const float4 s4 = *(const float4*)&bufS[(r0+i)*LDS_S + n0];
                float4 av;
                av.x = fmaxf(fmaf(s4.x, sra[i], b4.x), 0.f);
                av.y = fmaxf(fmaf(s4.y, sra[i], b4.y), 0.f);
                av.z = fmaxf(fmaf(s4.z, sra[i], b4.z), 0.f);
                av.w = fmaxf(fmaf(s4.w, sra[i], b4.w), 0.f);
                *(float4*)&bufA[swz(r0+i, n0)] = av;
                const float vv[4] = {av.x, av.y, av.z, av.w};
                short4_t h4s, l4s;
                #pragma unroll
                for (int c = 0; c < 4; ++c) {
                    const short hb = f2bf(vv[c]);
                    h4s[c] = hb;
                    l4s[c] = f2bf(vv[c] - bf2f(hb));
                }
                *(short4_t*)&xHi[(r0+i)*LDX + n0] = h4s;
                *(short4_t*)&xLo[(r0+i)*LDX + n0] = l4s;
            }
        }
        __syncthreads();
    }

    // ---- molecule sum + adduct concat (d2s reused for mv buffers) ----
    float* mv0 = d2s;
    float* mv1 = d2s + 256;
    if (t < DIMN) {
        float s = 0.f;
        #pragma unroll 4
        for (int r = 0; r < 32; ++r)
            s += bufA[(r << 8) + (t ^ (((r >> 2) & 7) << 2))];
        mv0[t] = s;
    } else if (t < DPD) {
        mv0[t] = adducts[mol*4 + (t - 200)];
    }
    __syncthreads();

    // ---- 3 pred layers on [204] vector ----
    float* pc = mv0;
    float* pn = mv1;
    for (int l = 0; l < 3; ++l) {
        if (t < DPD) {
            float acc = Wpb[l*DPD + t];
            const float* Wl = Wpw + l*DPD*DPD;
            #pragma unroll 4
            for (int k = 0; k < DPD; ++k)
                acc = fmaf(pc[k], Wl[k*DPD + t], acc);
            pn[t] = fmaxf(acc, 0.f);
        }
        __syncthreads();
        float* tp = pc; pc = pn; pn = tp;
    }

    // ---- final property head ----
    float v = (t < DPD) ? pc[t] * Wprw[t] : 0.f;
    #pragma unroll
    for (int m = 1; m < 64; m <<= 1) v += __shfl_xor(v, m);
    if (lane == 0) red16[w] = v;
    __syncthreads();
    if (t == 0) {
        float s = Wprb[0];
        #pragma unroll
        for (int ww = 0; ww < 13; ++ww) s += red16[ww];
        out[mol] = s;
    }
}

extern "C" void kernel_launch(void* const* d_in, const int* in_sizes, int n_in,
                              void* d_out, int out_size, void* d_ws, size_t ws_size,
                              hipStream_t stream) {
    const int*   atoms   = (const int*)  d_in[0];
    const float* dist    = (const float*)d_in[1];
    const float* adducts = (const float*)d_in[2];
    const float* embed   = (const float*)d_in[3];
    const float* gamma_t = (const float*)d_in[4];
    const float* Waw     = (const float*)d_in[5];
    const float* Wab     = (const float*)d_in[6];
    const float* Wow     = (const float*)d_in[7];
    const float* Wob     = (const float*)d_in[8];
    const float* Wpw     = (const float*)d_in[9];
    const float* Wpb     = (const float*)d_in[10];
    const float* Wprw    = (const float*)d_in[11];
    const float* Wprb    = (const float*)d_in[12];
    (void)in_sizes; (void)n_in; (void)ws_size; (void)out_size;

    short* W2 = (short*)d_ws;   // 9*WL shorts = ~1.68 MB

    conv_kernel<<<dim3(512), dim3(256), 0, stream>>>(Waw, Wow, W2);
    mgnn_kernel<<<dim3(256), dim3(832), 0, stream>>>(
        atoms, dist, adducts, embed, gamma_t,
        Waw, Wab, Wow, Wob, Wpw, Wpb, Wprw, Wprb,
        W2, (float*)d_out);
}